// Round 7
// baseline (553.562 us; speedup 1.0000x reference)
//
#include <hip/hip_runtime.h>
#include <hip/hip_bf16.h>

// Problem constants (from reference)
#define NNODES 10000
#define NEDGES 320000
#define INF_   1280
#define HID_   128
#define HEADS_ 4
#define OUTF_  500
#define HC_    512          // HEADS_*HID_
#define NEG_SLOPE 0.2f
#define BN_EPS 1e-5f

typedef __attribute__((ext_vector_type(8))) short short8x;
typedef __attribute__((ext_vector_type(4))) float f32x4;
typedef unsigned short ushort_t;
typedef unsigned int uint_t;

__device__ __forceinline__ ushort_t f2bf(float f) {
    uint_t u = __float_as_uint(f);
    u = (u + 0x7fffu + ((u >> 16) & 1u)) >> 16;   // round-to-nearest-even
    return (ushort_t)u;
}
__device__ __forceinline__ float bf_lo(uint_t p) { return __uint_as_float(p << 16); }
__device__ __forceinline__ float bf_hi(uint_t p) { return __uint_as_float(p & 0xffff0000u); }
__device__ __forceinline__ float lrelu(float x) { return (x >= 0.f) ? x : NEG_SLOPE * x; }

// ---------------------------------------------------------------------------
// utility kernels
// ---------------------------------------------------------------------------
__global__ void zero_kernel(float* __restrict__ p, size_t n) {
    size_t i = (size_t)blockIdx.x * blockDim.x + threadIdx.x;
    size_t stride = (size_t)gridDim.x * blockDim.x;
    for (; i < n; i += stride) p[i] = 0.0f;
}

// fp32 -> bf16 (flat)
__global__ void conv_bf16_kernel(const float* __restrict__ in, ushort_t* __restrict__ out, int n) {
    int i = blockIdx.x * blockDim.x + threadIdx.x;
    if (i < n) out[i] = f2bf(in[i]);
}

// fp32 W[K][N] -> bf16 Wt[Npad][K]  (write-coalesced; rows [N,Npad) zeroed)
__global__ void transconv_kernel(const float* __restrict__ W, ushort_t* __restrict__ Wt,
                                 int K, int N, int Npad) {
    int i = blockIdx.x * blockDim.x + threadIdx.x;
    if (i < Npad * K) {
        int n = i / K;
        int k = i - n * K;
        Wt[i] = (n < N) ? f2bf(W[(size_t)k * N + n]) : (ushort_t)0;
    }
}

// ---------------------------------------------------------------------------
// CSR build (by destination) — hierarchical scan, built once per call
// ---------------------------------------------------------------------------
__global__ void count_kernel(const int* __restrict__ dst, int* __restrict__ counts, int E) {
    int e = blockIdx.x * blockDim.x + threadIdx.x;
    if (e < E) atomicAdd(&counts[dst[e]], 1);
}

// phase 1: per-256 block exclusive scan (no base), block sums out
__global__ __launch_bounds__(256) void scan1_kernel(const int* __restrict__ counts,
                                                    int* __restrict__ offsets,
                                                    int* __restrict__ bsum, int n) {
    __shared__ int tmp[256];
    int b = blockIdx.x, t = threadIdx.x;
    int i = b * 256 + t;
    int v = (i < n) ? counts[i] : 0;
    tmp[t] = v;
    __syncthreads();
    for (int off = 1; off < 256; off <<= 1) {
        int u = (t >= off) ? tmp[t - off] : 0;
        __syncthreads();
        tmp[t] += u;
        __syncthreads();
    }
    if (i < n) offsets[i] = tmp[t] - v;
    if (t == 255) bsum[b] = tmp[t];
}

// phase 2: serial exclusive scan of block sums (tiny)
__global__ void scan2_kernel(const int* __restrict__ bsum, int* __restrict__ bbase,
                             int* __restrict__ offsets, int nb, int n) {
    if (threadIdx.x == 0) {
        int acc = 0;
        for (int b = 0; b < nb; ++b) { bbase[b] = acc; acc += bsum[b]; }
        offsets[n] = acc;
    }
}

// phase 3: add block bases; also produce cursor copy for scatter
__global__ void scan3_kernel(int* __restrict__ offsets, int* __restrict__ cursor,
                             const int* __restrict__ bbase, int n) {
    int i = blockIdx.x * 256 + threadIdx.x;
    if (i < n) {
        int v = offsets[i] + bbase[i >> 8];
        offsets[i] = v;
        cursor[i] = v;
    }
}

__global__ void scatter_kernel(const int* __restrict__ src, const int* __restrict__ dst,
                               int* __restrict__ cursor, int* __restrict__ esrc, int E) {
    int e = blockIdx.x * blockDim.x + threadIdx.x;
    if (e < E) {
        int p = atomicAdd(&cursor[dst[e]], 1);
        esrc[p] = src[e];
    }
}

// ---------------------------------------------------------------------------
// bf16 MFMA GEMM with fused attention-logit epilogue.
//   C[M,512] = A[M,K] @ Bt[512,K]^T (bf16 out, row stride 512, pad cols zero
//   via zero-padded Bt rows).
//   Tile: 128 (M) x 64 (N), BK=64. 256 thr = 4 waves; wave = 64x32 sub-tile
//   = 4x2 grid of 16x16 MFMAs x 2 k-steps -> 16 MFMAs between barrier pairs
//   (4x the previous structure; attacks the barrier-drain stall seen at
//   MfmaUtil 8.9%).
//   1-D grid, XCD-swizzled: the 8 col-blocks of a row-block share id%8 so A
//   stays L2-resident per XCD (FETCH 100->17.7 MB verified in R6).
//   Epilogue: C store + per-row logit partials (shfl-reduce + atomicAdd).
// ---------------------------------------------------------------------------
#define LDTK 72   // LDS row stride in ushorts for BK=64 (+8 pad: 2-way banks max)

__global__ __launch_bounds__(256) void gemm_fused_kernel(
    const ushort_t* __restrict__ A,    // [M][K] bf16
    const ushort_t* __restrict__ Bt,   // [512][K] bf16 (transposed, padded)
    ushort_t* __restrict__ Cb,         // [M][512] bf16
    const float* __restrict__ avS,     // a_src flat [N]
    const float* __restrict__ avD,     // a_dst flat [N]
    float* __restrict__ s_log,         // [M][H] (pre-zeroed)
    float* __restrict__ d_log,         // [M][H]
    int M, int K, int N, int H, int nMB)
{
    __shared__ __align__(16) ushort_t As[128 * LDTK];
    __shared__ __align__(16) ushort_t Bs[64 * LDTK];

    // swizzle: mb = g*8 + (id&7), nb = (id>>3)&7  -> col-blocks share XCD
    int id = blockIdx.x;
    int mb = (id >> 6) * 8 + (id & 7);
    int nb = (id >> 3) & 7;
    if (mb >= nMB) return;
    int m0 = mb * 128, n0 = nb * 64;

    int tid  = threadIdx.x;
    int lane = tid & 63;
    int w    = tid >> 6;
    int wm   = (w & 1) * 64;       // wave m-offset within tile
    int wn   = (w >> 1) * 32;      // wave n-offset within tile
    int quad = lane >> 4;
    int c16  = lane & 15;

    f32x4 acc[4][2];
#pragma unroll
    for (int i = 0; i < 4; ++i)
#pragma unroll
        for (int j = 0; j < 2; ++j)
#pragma unroll
            for (int r = 0; r < 4; ++r) acc[i][j][r] = 0.0f;

    for (int k0 = 0; k0 < K; k0 += 64) {
        // stage A tile 128x64 (4 chunks/thread) and B tile 64x64 (2 chunks)
#pragma unroll
        for (int t = 0; t < 4; ++t) {
            int ci = t * 256 + tid;
            int row = ci >> 3;
            int kc = (ci & 7) * 8;
            int gm = m0 + row;
            if (gm > M - 1) gm = M - 1;    // clamp tail rows (stores masked)
            uint4 av = *(const uint4*)(A + (size_t)gm * K + k0 + kc);
            *(uint4*)&As[row * LDTK + kc] = av;
        }
#pragma unroll
        for (int t = 0; t < 2; ++t) {
            int ci = t * 256 + tid;
            int row = ci >> 3;
            int kc = (ci & 7) * 8;
            uint4 bv = *(const uint4*)(Bt + (size_t)(n0 + row) * K + k0 + kc);
            *(uint4*)&Bs[row * LDTK + kc] = bv;
        }
        __syncthreads();

#pragma unroll
        for (int ks = 0; ks < 2; ++ks) {
            short8x af[4], bf[2];
#pragma unroll
            for (int mt = 0; mt < 4; ++mt)
                af[mt] = *(const short8x*)&As[(wm + mt * 16 + c16) * LDTK + ks * 32 + quad * 8];
#pragma unroll
            for (int nt = 0; nt < 2; ++nt)
                bf[nt] = *(const short8x*)&Bs[(wn + nt * 16 + c16) * LDTK + ks * 32 + quad * 8];
#pragma unroll
            for (int mt = 0; mt < 4; ++mt)
#pragma unroll
                for (int nt = 0; nt < 2; ++nt)
                    acc[mt][nt] = __builtin_amdgcn_mfma_f32_16x16x32_bf16(
                        af[mt], bf[nt], acc[mt][nt], 0, 0, 0);
        }
        __syncthreads();
    }

    // ---- epilogue: C store + logit partials ----
    int col0 = n0 + wn + c16;
    int col1 = col0 + 16;
    float as0 = (col0 < N) ? avS[col0] : 0.f;
    float as1 = (col1 < N) ? avS[col1] : 0.f;
    float ad0 = (col0 < N) ? avD[col0] : 0.f;
    float ad1 = (col1 < N) ? avD[col1] : 0.f;

    float sv[16], dv[16];   // [mt*4+r]
#pragma unroll
    for (int mt = 0; mt < 4; ++mt) {
#pragma unroll
        for (int r = 0; r < 4; ++r) {
            float v0 = acc[mt][0][r];
            float v1 = acc[mt][1][r];
            sv[mt * 4 + r] = v0 * as0 + v1 * as1;
            dv[mt * 4 + r] = v0 * ad0 + v1 * ad1;
            int row = m0 + wm + mt * 16 + quad * 4 + r;
            if (row < M) {
                Cb[(size_t)row * 512 + col0] = f2bf(v0);
                Cb[(size_t)row * 512 + col1] = f2bf(v1);
            }
        }
    }
    // reduce over the 16 c16 lanes (xor<16 stays within the 16-lane group)
#pragma unroll
    for (int off = 1; off < 16; off <<= 1) {
#pragma unroll
        for (int i = 0; i < 16; ++i) {
            sv[i] += __shfl_xor(sv[i], off);
            dv[i] += __shfl_xor(dv[i], off);
        }
    }
    if (c16 == 0) {
        int hb = (H == 4) ? (n0 >> 7) : 0;   // 64-wide tile sits in one head
#pragma unroll
        for (int mt = 0; mt < 4; ++mt) {
#pragma unroll
            for (int r = 0; r < 4; ++r) {
                int row = m0 + wm + mt * 16 + quad * 4 + r;
                if (row < M) {
                    atomicAdd(&s_log[row * H + hb], sv[mt * 4 + r]);
                    atomicAdd(&d_log[row * H + hb], dv[mt * 4 + r]);
                }
            }
        }
    }
}

// ---------------------------------------------------------------------------
// scalar softmax over each dst's edge list: one wave per dst node.
// ---------------------------------------------------------------------------
template<int H>
__global__ __launch_bounds__(64) void edge_softmax_kernel(
    const float* __restrict__ s,     // [node][H]
    const float* __restrict__ dlog,  // [node][H]
    const int* __restrict__ offsets, const int* __restrict__ esrc,
    float* __restrict__ ew,          // [E][H] unnormalized exp weights
    float* __restrict__ wself,       // [node][H]
    float* __restrict__ zinv)        // [node][H]
{
    int dst = blockIdx.x;
    int lane = threadIdx.x;
    int e0 = offsets[dst], e1 = offsets[dst + 1];

    float dh[H], selfe[H], mh[H], zh[H];
#pragma unroll
    for (int h = 0; h < H; ++h) {
        dh[h] = dlog[dst * H + h];
        selfe[h] = lrelu(s[dst * H + h] + dh[h]);
        mh[h] = selfe[h];
        zh[h] = 0.f;
    }

    // pass 1: max
    for (int j = e0 + lane; j < e1; j += 64) {
        int src = esrc[j];
        if (H == 4) {
            float4 sv = ((const float4*)s)[src];
            mh[0] = fmaxf(mh[0], lrelu(sv.x + dh[0]));
            mh[1] = fmaxf(mh[1], lrelu(sv.y + dh[1]));
            mh[2] = fmaxf(mh[2], lrelu(sv.z + dh[2]));
            mh[3] = fmaxf(mh[3], lrelu(sv.w + dh[3]));
        } else {
#pragma unroll
            for (int h = 0; h < H; ++h)
                mh[h] = fmaxf(mh[h], lrelu(s[src * H + h] + dh[h]));
        }
    }
#pragma unroll
    for (int h = 0; h < H; ++h)
        for (int off = 32; off > 0; off >>= 1)
            mh[h] = fmaxf(mh[h], __shfl_xor(mh[h], off));

    // pass 2: w = exp(e - m), store, sum
    for (int j = e0 + lane; j < e1; j += 64) {
        int src = esrc[j];
        if (H == 4) {
            float4 sv = ((const float4*)s)[src];
            float w0 = __expf(lrelu(sv.x + dh[0]) - mh[0]);
            float w1 = __expf(lrelu(sv.y + dh[1]) - mh[1]);
            float w2 = __expf(lrelu(sv.z + dh[2]) - mh[2]);
            float w3 = __expf(lrelu(sv.w + dh[3]) - mh[3]);
            ((float4*)ew)[j] = make_float4(w0, w1, w2, w3);
            zh[0] += w0; zh[1] += w1; zh[2] += w2; zh[3] += w3;
        } else {
#pragma unroll
            for (int h = 0; h < H; ++h) {
                float w = __expf(lrelu(s[src * H + h] + dh[h]) - mh[h]);
                ew[(size_t)j * H + h] = w;
                zh[h] += w;
            }
        }
    }
#pragma unroll
    for (int h = 0; h < H; ++h)
        for (int off = 32; off > 0; off >>= 1)
            zh[h] += __shfl_xor(zh[h], off);

    if (lane == 0) {
#pragma unroll
        for (int h = 0; h < H; ++h) {
            float ws = __expf(selfe[h] - mh[h]);
            wself[dst * H + h] = ws;
            zinv[dst * H + h] = 1.0f / (zh[h] + ws);
        }
    }
}

// ---------------------------------------------------------------------------
// weighted gather-aggregate, wave-per-node, uint4 (16B/lane = 1KB/row/inst).
// ---------------------------------------------------------------------------
__device__ __forceinline__ void acc8(float* acc, uint4 q, float w) {
    acc[0] += w * bf_lo(q.x); acc[1] += w * bf_hi(q.x);
    acc[2] += w * bf_lo(q.y); acc[3] += w * bf_hi(q.y);
    acc[4] += w * bf_lo(q.z); acc[5] += w * bf_hi(q.z);
    acc[6] += w * bf_lo(q.w); acc[7] += w * bf_hi(q.w);
}

template<int H>
__global__ __launch_bounds__(256) void aggregate3_kernel(
    const uint4* __restrict__ xpb4,     // [node][64]
    const int* __restrict__ offsets, const int* __restrict__ esrc,
    const float* __restrict__ ew,       // [E][H]
    const float* __restrict__ wself,    // [node][H]
    const float* __restrict__ zinv,     // [node][H]
    const float* __restrict__ bias,     // [OUTC]
    float* __restrict__ out,            // [node][ldo]
    int OUTC, int ldo)
{
    int node = blockIdx.x * 4 + (threadIdx.x >> 6);
    if (node >= NNODES) return;
    int lane = threadIdx.x & 63;
    int h = (H == 4) ? (lane >> 4) : 0;   // 8 ch/lane, 128 ch/head

    float ws = wself[node * H + h];
    uint4 p = xpb4[(size_t)node * 64 + lane];
    float acc[8];
    acc[0] = ws * bf_lo(p.x); acc[1] = ws * bf_hi(p.x);
    acc[2] = ws * bf_lo(p.y); acc[3] = ws * bf_hi(p.y);
    acc[4] = ws * bf_lo(p.z); acc[5] = ws * bf_hi(p.z);
    acc[6] = ws * bf_lo(p.w); acc[7] = ws * bf_hi(p.w);

    int e0 = offsets[node], e1 = offsets[node + 1];
    int j = e0;
    for (; j + 3 < e1; j += 4) {
        int s0 = esrc[j], s1 = esrc[j + 1], s2 = esrc[j + 2], s3 = esrc[j + 3];
        float w0 = ew[(size_t)j * H + h];
        float w1 = ew[(size_t)(j + 1) * H + h];
        float w2 = ew[(size_t)(j + 2) * H + h];
        float w3 = ew[(size_t)(j + 3) * H + h];
        uint4 q0 = xpb4[(size_t)s0 * 64 + lane];
        uint4 q1 = xpb4[(size_t)s1 * 64 + lane];
        uint4 q2 = xpb4[(size_t)s2 * 64 + lane];
        uint4 q3 = xpb4[(size_t)s3 * 64 + lane];
        acc8(acc, q0, w0);
        acc8(acc, q1, w1);
        acc8(acc, q2, w2);
        acc8(acc, q3, w3);
    }
    for (; j < e1; ++j) {
        int s0 = esrc[j];
        float w0 = ew[(size_t)j * H + h];
        uint4 q0 = xpb4[(size_t)s0 * 64 + lane];
        acc8(acc, q0, w0);
    }

    float zi = zinv[node * H + h];
    int cbase = lane * 8;
    size_t ob = (size_t)node * ldo + cbase;
    if (cbase + 7 < OUTC) {
        float4 o0 = make_float4(acc[0] * zi + bias[cbase + 0], acc[1] * zi + bias[cbase + 1],
                                acc[2] * zi + bias[cbase + 2], acc[3] * zi + bias[cbase + 3]);
        float4 o1 = make_float4(acc[4] * zi + bias[cbase + 4], acc[5] * zi + bias[cbase + 5],
                                acc[6] * zi + bias[cbase + 6], acc[7] * zi + bias[cbase + 7]);
        *(float4*)(out + ob) = o0;
        *(float4*)(out + ob + 4) = o1;
    } else {
#pragma unroll
        for (int k = 0; k < 8; ++k) {
            int c = cbase + k;
            if (c < OUTC) out[ob + k] = acc[k] * zi + bias[c];
        }
    }
}

// ---------------------------------------------------------------------------
// BatchNorm (training normalization, biased var) + ELU -> bf16
// partial-sum version: no zero-init, no atomics.
// ---------------------------------------------------------------------------
__global__ __launch_bounds__(512) void bn_stats_kernel(const float* __restrict__ h,
                                                       float* __restrict__ psum,
                                                       float* __restrict__ psumsq,
                                                       int Nrows) {
    int c = threadIdx.x;  // 512
    int b = blockIdx.x;   // 64
    float sm = 0.f, sq = 0.f;
    for (int r = b; r < Nrows; r += 64) {
        float v = h[(size_t)r * 512 + c];
        sm += v;
        sq += v * v;
    }
    psum[b * 512 + c] = sm;
    psumsq[b * 512 + c] = sq;
}

__global__ __launch_bounds__(512) void bn_finalize_kernel(const float* __restrict__ psum,
                                                          const float* __restrict__ psumsq,
                                                          const float* __restrict__ gamma,
                                                          const float* __restrict__ beta,
                                                          float* __restrict__ scale,
                                                          float* __restrict__ shift,
                                                          int Nrows) {
    int c = threadIdx.x;
    float sm = 0.f, sq = 0.f;
    for (int b = 0; b < 64; ++b) {
        sm += psum[b * 512 + c];
        sq += psumsq[b * 512 + c];
    }
    float mu = sm / (float)Nrows;
    float var = sq / (float)Nrows - mu * mu;
    float sc = gamma[c] * rsqrtf(var + BN_EPS);
    scale[c] = sc;
    shift[c] = beta[c] - mu * sc;
}

// h fp32 [N][512] -> hbf packed bf16 pairs [N][256]
__global__ void bn_apply_elu_bf16_kernel(const float* __restrict__ h,
                                         const float* __restrict__ scale,
                                         const float* __restrict__ shift,
                                         uint_t* __restrict__ hbf,
                                         int npairs) {
    int i = blockIdx.x * blockDim.x + threadIdx.x;
    if (i < npairs) {
        int c0 = (i & 255) * 2;   // Ncols = 512
        float2 hv = ((const float2*)h)[i];
        float v0 = hv.x * scale[c0]     + shift[c0];
        float v1 = hv.y * scale[c0 + 1] + shift[c0 + 1];
        v0 = (v0 > 0.f) ? v0 : (__expf(v0) - 1.0f);
        v1 = (v1 > 0.f) ? v1 : (__expf(v1) - 1.0f);
        hbf[i] = ((uint_t)f2bf(v1) << 16) | (uint_t)f2bf(v0);
    }
}

// ---------------------------------------------------------------------------
// launch
// ---------------------------------------------------------------------------
extern "C" void kernel_launch(void* const* d_in, const int* in_sizes, int n_in,
                              void* d_out, int out_size, void* d_ws, size_t ws_size,
                              hipStream_t stream) {
    const float* x      = (const float*)d_in[0];
    const int*   ei     = (const int*)d_in[1];
    const float* W1     = (const float*)d_in[2];
    const float* a_src1 = (const float*)d_in[3];
    const float* a_dst1 = (const float*)d_in[4];
    const float* b1     = (const float*)d_in[5];
    const float* g1     = (const float*)d_in[6];
    const float* be1    = (const float*)d_in[7];
    const float* W2     = (const float*)d_in[8];
    const float* a_src2 = (const float*)d_in[9];
    const float* a_dst2 = (const float*)d_in[10];
    const float* b2     = (const float*)d_in[11];
    const float* g2     = (const float*)d_in[12];
    const float* be2    = (const float*)d_in[13];
    const float* W3     = (const float*)d_in[14];
    const float* a_src3 = (const float*)d_in[15];
    const float* a_dst3 = (const float*)d_in[16];
    const float* b3     = (const float*)d_in[17];
    float* out = (float*)d_out;

    const int* e_src = ei;           // edge_index[0]
    const int* e_dst = ei + NEDGES;  // edge_index[1]

    // ---- workspace layout ----
    char* w = (char*)d_ws;
    // region 0: x_bf (25.6 MB), later reused as hbuf fp32 (20.48 MB) + ew (5.12 MB)
    ushort_t* x_bf = (ushort_t*)w;
    float*    hbuf = (float*)w;                               // alias after L1 GEMM
    float*    ew   = (float*)(w + (size_t)NNODES * HC_ * sizeof(float));  // tail 5.12 MB
    w += (size_t)NNODES * INF_ * sizeof(ushort_t);            // 25,600,000
    uint_t* xpb = (uint_t*)w;  w += (size_t)NNODES * HC_ * sizeof(ushort_t);   // 10,240,000
    uint_t* hbf = (uint_t*)w;  w += (size_t)NNODES * HC_ * sizeof(ushort_t);   // 10,240,000
    ushort_t* Wt1 = (ushort_t*)w; w += (size_t)INF_ * HC_ * sizeof(ushort_t);  // 1,310,720
    ushort_t* Wt2 = (ushort_t*)w; w += (size_t)HC_ * HC_ * sizeof(ushort_t);   //   524,288
    ushort_t* Wt3 = (ushort_t*)w; w += (size_t)HC_ * HC_ * sizeof(ushort_t);   //   524,288 (padded 512 rows)
    // counts, s_log, d_log contiguous -> single zero pass
    int* counts  = (int*)w;    w += NNODES * sizeof(int);
    float* s_log = (float*)w;  w += NNODES * HEADS_ * sizeof(float);
    float* d_log = (float*)w;  w += NNODES * HEADS_ * sizeof(float);
    float* wself = (float*)w;  w += NNODES * HEADS_ * sizeof(float);
    float* zinv  = (float*)w;  w += NNODES * HEADS_ * sizeof(float);
    float* bnscale = (float*)w; w += HC_ * sizeof(float);
    float* bnshift = (float*)w; w += HC_ * sizeof(float);
    float* psum  = (float*)w;  w += 64 * HC_ * sizeof(float);
    float* psumsq= (float*)w;  w += 64 * HC_ * sizeof(float);
    int* offsets = (int*)w;    w += (NNODES + 1) * sizeof(int);
    int* cursor  = (int*)w;    w += NNODES * sizeof(int);
    int* esrc    = (int*)w;    w += NEDGES * sizeof(int);
    int* bsum    = (int*)w;    w += 64 * sizeof(int);
    int* bbase   = (int*)w;    w += 64 * sizeof(int);

    const int nMB = (NNODES + 127) / 128;            // 79 row blocks (128 rows)
    const int gemmBlocks = ((nMB + 7) / 8) * 64;     // swizzled 1-D grid (640)
    int aggGrid = (NNODES + 3) / 4;
    const int scanBlocks = (NNODES + 255) / 256;     // 40

    // ---- CSR build + zero (counts | s_log | d_log share one zero pass) ----
    zero_kernel<<<64, 256, 0, stream>>>((float*)counts, NNODES + 2 * NNODES * HEADS_);
    count_kernel<<<(NEDGES + 255) / 256, 256, 0, stream>>>(e_dst, counts, NEDGES);
    scan1_kernel<<<scanBlocks, 256, 0, stream>>>(counts, offsets, bsum, NNODES);
    scan2_kernel<<<1, 64, 0, stream>>>(bsum, bbase, offsets, scanBlocks, NNODES);
    scan3_kernel<<<scanBlocks, 256, 0, stream>>>(offsets, cursor, bbase, NNODES);
    scatter_kernel<<<(NEDGES + 255) / 256, 256, 0, stream>>>(e_src, e_dst, cursor, esrc, NEDGES);

    // ---- bf16 conversions (x and transposed weights; Wt3 zero-padded) ----
    {
        int nx = NNODES * INF_;
        conv_bf16_kernel<<<(nx + 255) / 256, 256, 0, stream>>>(x, x_bf, nx);
        int n1 = INF_ * HC_;
        transconv_kernel<<<(n1 + 255) / 256, 256, 0, stream>>>(W1, Wt1, INF_, HC_, HC_);
        int n2 = HC_ * HC_;
        transconv_kernel<<<(n2 + 255) / 256, 256, 0, stream>>>(W2, Wt2, HC_, HC_, HC_);
        int n3 = HC_ * HC_;
        transconv_kernel<<<(n3 + 255) / 256, 256, 0, stream>>>(W3, Wt3, HC_, OUTF_, HC_);
    }

    // ---- Layer 1 ----   (x_bf dead after its GEMM; hbuf/ew alias its region)
    gemm_fused_kernel<<<gemmBlocks, 256, 0, stream>>>(x_bf, Wt1, (ushort_t*)xpb,
        a_src1, a_dst1, s_log, d_log, NNODES, INF_, HC_, HEADS_, nMB);
    edge_softmax_kernel<HEADS_><<<NNODES, 64, 0, stream>>>(s_log, d_log, offsets, esrc, ew, wself, zinv);
    aggregate3_kernel<HEADS_><<<aggGrid, 256, 0, stream>>>((const uint4*)xpb, offsets, esrc, ew, wself, zinv, b1, hbuf, HC_, HC_);
    bn_stats_kernel<<<64, 512, 0, stream>>>(hbuf, psum, psumsq, NNODES);
    bn_finalize_kernel<<<1, 512, 0, stream>>>(psum, psumsq, g1, be1, bnscale, bnshift, NNODES);
    bn_apply_elu_bf16_kernel<<<(NNODES * 256 + 255) / 256, 256, 0, stream>>>(hbuf, bnscale, bnshift, hbf, NNODES * 256);

    // ---- Layer 2 ----
    zero_kernel<<<32, 256, 0, stream>>>(s_log, 2 * NNODES * HEADS_);
    gemm_fused_kernel<<<gemmBlocks, 256, 0, stream>>>((const ushort_t*)hbf, Wt2, (ushort_t*)xpb,
        a_src2, a_dst2, s_log, d_log, NNODES, HC_, HC_, HEADS_, nMB);
    edge_softmax_kernel<HEADS_><<<NNODES, 64, 0, stream>>>(s_log, d_log, offsets, esrc, ew, wself, zinv);
    aggregate3_kernel<HEADS_><<<aggGrid, 256, 0, stream>>>((const uint4*)xpb, offsets, esrc, ew, wself, zinv, b2, hbuf, HC_, HC_);
    bn_stats_kernel<<<64, 512, 0, stream>>>(hbuf, psum, psumsq, NNODES);
    bn_finalize_kernel<<<1, 512, 0, stream>>>(psum, psumsq, g2, be2, bnscale, bnshift, NNODES);
    bn_apply_elu_bf16_kernel<<<(NNODES * 256 + 255) / 256, 256, 0, stream>>>(hbuf, bnscale, bnshift, hbf, NNODES * 256);

    // ---- Layer 3 (H=1, N=500; Wt3 zero-padded so xp pad cols are true zeros) ----
    zero_kernel<<<32, 256, 0, stream>>>(s_log, 2 * NNODES * HEADS_);
    gemm_fused_kernel<<<gemmBlocks, 256, 0, stream>>>((const ushort_t*)hbf, Wt3, (ushort_t*)xpb,
        a_src3, a_dst3, s_log, d_log, NNODES, HC_, OUTF_, 1, nMB);
    edge_softmax_kernel<1><<<NNODES, 64, 0, stream>>>(s_log, d_log, offsets, esrc, ew, wself, zinv);
    aggregate3_kernel<1><<<aggGrid, 256, 0, stream>>>((const uint4*)xpb, offsets, esrc, ew, wself, zinv, b3, out, OUTF_, OUTF_);
}

// Round 8
// 539.490 us; speedup vs baseline: 1.0261x; 1.0261x over previous
//
#include <hip/hip_runtime.h>
#include <hip/hip_bf16.h>

// Problem constants (from reference)
#define NNODES 10000
#define NEDGES 320000
#define INF_   1280
#define HID_   128
#define HEADS_ 4
#define OUTF_  500
#define HC_    512          // HEADS_*HID_
#define NEG_SLOPE 0.2f
#define BN_EPS 1e-5f

typedef __attribute__((ext_vector_type(8))) short short8x;
typedef __attribute__((ext_vector_type(4))) float f32x4;
typedef unsigned short ushort_t;
typedef unsigned int uint_t;

__device__ __forceinline__ ushort_t f2bf(float f) {
    uint_t u = __float_as_uint(f);
    u = (u + 0x7fffu + ((u >> 16) & 1u)) >> 16;   // round-to-nearest-even
    return (ushort_t)u;
}
__device__ __forceinline__ float bf_lo(uint_t p) { return __uint_as_float(p << 16); }
__device__ __forceinline__ float bf_hi(uint_t p) { return __uint_as_float(p & 0xffff0000u); }
__device__ __forceinline__ float lrelu(float x) { return (x >= 0.f) ? x : NEG_SLOPE * x; }

// ---------------------------------------------------------------------------
// utility
// ---------------------------------------------------------------------------
__global__ void zero_kernel(float* __restrict__ p, size_t n) {
    size_t i = (size_t)blockIdx.x * blockDim.x + threadIdx.x;
    size_t stride = (size_t)gridDim.x * blockDim.x;
    for (; i < n; i += stride) p[i] = 0.0f;
}

// one kernel: x->bf16 + 3 weight transposes (cuts 3 dispatches)
#define CNX (NNODES * INF_)            // 12,800,000
#define CN1 (HC_ * INF_)               // Wt1: 512 rows x 1280
#define CN2 (HC_ * HC_)                // Wt2
#define CN3 (HC_ * HC_)                // Wt3 (padded rows)
__global__ void convall_kernel(const float* __restrict__ x,
                               const float* __restrict__ W1,
                               const float* __restrict__ W2,
                               const float* __restrict__ W3,
                               ushort_t* __restrict__ x_bf,
                               ushort_t* __restrict__ Wt1,
                               ushort_t* __restrict__ Wt2,
                               ushort_t* __restrict__ Wt3) {
    int i = blockIdx.x * blockDim.x + threadIdx.x;
    if (i < CNX) {
        x_bf[i] = f2bf(x[i]);
    } else if (i < CNX + CN1) {
        int j = i - CNX;
        int n = j / INF_, k = j - n * INF_;
        Wt1[j] = f2bf(W1[(size_t)k * HC_ + n]);
    } else if (i < CNX + CN1 + CN2) {
        int j = i - CNX - CN1;
        int n = j / HC_, k = j - n * HC_;
        Wt2[j] = f2bf(W2[(size_t)k * HC_ + n]);
    } else if (i < CNX + CN1 + CN2 + CN3) {
        int j = i - CNX - CN1 - CN2;
        int n = j / HC_, k = j - n * HC_;
        Wt3[j] = (n < OUTF_) ? f2bf(W3[(size_t)k * OUTF_ + n]) : (ushort_t)0;
    }
}

// ---------------------------------------------------------------------------
// CSR build (by destination)
// ---------------------------------------------------------------------------
__global__ void count_kernel(const int* __restrict__ dst, int* __restrict__ counts, int E) {
    int e = blockIdx.x * blockDim.x + threadIdx.x;
    if (e < E) atomicAdd(&counts[dst[e]], 1);
}

// phase 1: per-256 block exclusive scan, block sums out
__global__ __launch_bounds__(256) void scan1_kernel(const int* __restrict__ counts,
                                                    int* __restrict__ offsets,
                                                    int* __restrict__ bsum, int n) {
    __shared__ int tmp[256];
    int b = blockIdx.x, t = threadIdx.x;
    int i = b * 256 + t;
    int v = (i < n) ? counts[i] : 0;
    tmp[t] = v;
    __syncthreads();
    for (int off = 1; off < 256; off <<= 1) {
        int u = (t >= off) ? tmp[t - off] : 0;
        __syncthreads();
        tmp[t] += u;
        __syncthreads();
    }
    if (i < n) offsets[i] = tmp[t] - v;
    if (t == 255) bsum[b] = tmp[t];
}

// phase 2 (merged): each block serially computes its base from bsum, adds it,
// writes cursor copy; last block writes offsets[n]
__global__ __launch_bounds__(256) void scan3b_kernel(int* __restrict__ offsets,
                                                     int* __restrict__ cursor,
                                                     const int* __restrict__ bsum,
                                                     int nb, int n) {
    __shared__ int base_sh, tot_sh;
    int b = blockIdx.x, t = threadIdx.x;
    if (t == 0) {
        int acc = 0, tot = 0;
        for (int k = 0; k < nb; ++k) { if (k < b) acc += bsum[k]; tot += bsum[k]; }
        base_sh = acc; tot_sh = tot;
    }
    __syncthreads();
    int i = b * 256 + t;
    if (i < n) {
        int v = offsets[i] + base_sh;
        offsets[i] = v;
        cursor[i] = v;
    }
    if (b == nb - 1 && t == 0) offsets[n] = tot_sh;
}

__global__ void scatter_kernel(const int* __restrict__ src, const int* __restrict__ dst,
                               int* __restrict__ cursor, int* __restrict__ esrc, int E) {
    int e = blockIdx.x * blockDim.x + threadIdx.x;
    if (e < E) {
        int p = atomicAdd(&cursor[dst[e]], 1);
        esrc[p] = src[e];
    }
}

// ---------------------------------------------------------------------------
// bf16 MFMA GEMM with fused attention-logit epilogue (unchanged from R7).
// ---------------------------------------------------------------------------
#define LDTK 72

__global__ __launch_bounds__(256) void gemm_fused_kernel(
    const ushort_t* __restrict__ A,    // [M][K] bf16
    const ushort_t* __restrict__ Bt,   // [512][K] bf16 (transposed, padded)
    ushort_t* __restrict__ Cb,         // [M][512] bf16
    const float* __restrict__ avS,     // a_src flat [N]
    const float* __restrict__ avD,     // a_dst flat [N]
    float* __restrict__ s_log,         // [M][H] (pre-zeroed)
    float* __restrict__ d_log,         // [M][H]
    int M, int K, int N, int H, int nMB)
{
    __shared__ __align__(16) ushort_t As[128 * LDTK];
    __shared__ __align__(16) ushort_t Bs[64 * LDTK];

    int id = blockIdx.x;
    int mb = (id >> 6) * 8 + (id & 7);
    int nb = (id >> 3) & 7;
    if (mb >= nMB) return;
    int m0 = mb * 128, n0 = nb * 64;

    int tid  = threadIdx.x;
    int lane = tid & 63;
    int w    = tid >> 6;
    int wm   = (w & 1) * 64;
    int wn   = (w >> 1) * 32;
    int quad = lane >> 4;
    int c16  = lane & 15;

    f32x4 acc[4][2];
#pragma unroll
    for (int i = 0; i < 4; ++i)
#pragma unroll
        for (int j = 0; j < 2; ++j)
#pragma unroll
            for (int r = 0; r < 4; ++r) acc[i][j][r] = 0.0f;

    for (int k0 = 0; k0 < K; k0 += 64) {
#pragma unroll
        for (int t = 0; t < 4; ++t) {
            int ci = t * 256 + tid;
            int row = ci >> 3;
            int kc = (ci & 7) * 8;
            int gm = m0 + row;
            if (gm > M - 1) gm = M - 1;
            uint4 av = *(const uint4*)(A + (size_t)gm * K + k0 + kc);
            *(uint4*)&As[row * LDTK + kc] = av;
        }
#pragma unroll
        for (int t = 0; t < 2; ++t) {
            int ci = t * 256 + tid;
            int row = ci >> 3;
            int kc = (ci & 7) * 8;
            uint4 bv = *(const uint4*)(Bt + (size_t)(n0 + row) * K + k0 + kc);
            *(uint4*)&Bs[row * LDTK + kc] = bv;
        }
        __syncthreads();

#pragma unroll
        for (int ks = 0; ks < 2; ++ks) {
            short8x af[4], bf[2];
#pragma unroll
            for (int mt = 0; mt < 4; ++mt)
                af[mt] = *(const short8x*)&As[(wm + mt * 16 + c16) * LDTK + ks * 32 + quad * 8];
#pragma unroll
            for (int nt = 0; nt < 2; ++nt)
                bf[nt] = *(const short8x*)&Bs[(wn + nt * 16 + c16) * LDTK + ks * 32 + quad * 8];
#pragma unroll
            for (int mt = 0; mt < 4; ++mt)
#pragma unroll
                for (int nt = 0; nt < 2; ++nt)
                    acc[mt][nt] = __builtin_amdgcn_mfma_f32_16x16x32_bf16(
                        af[mt], bf[nt], acc[mt][nt], 0, 0, 0);
        }
        __syncthreads();
    }

    int col0 = n0 + wn + c16;
    int col1 = col0 + 16;
    float as0 = (col0 < N) ? avS[col0] : 0.f;
    float as1 = (col1 < N) ? avS[col1] : 0.f;
    float ad0 = (col0 < N) ? avD[col0] : 0.f;
    float ad1 = (col1 < N) ? avD[col1] : 0.f;

    float sv[16], dv[16];
#pragma unroll
    for (int mt = 0; mt < 4; ++mt) {
#pragma unroll
        for (int r = 0; r < 4; ++r) {
            float v0 = acc[mt][0][r];
            float v1 = acc[mt][1][r];
            sv[mt * 4 + r] = v0 * as0 + v1 * as1;
            dv[mt * 4 + r] = v0 * ad0 + v1 * ad1;
            int row = m0 + wm + mt * 16 + quad * 4 + r;
            if (row < M) {
                Cb[(size_t)row * 512 + col0] = f2bf(v0);
                Cb[(size_t)row * 512 + col1] = f2bf(v1);
            }
        }
    }
#pragma unroll
    for (int off = 1; off < 16; off <<= 1) {
#pragma unroll
        for (int i = 0; i < 16; ++i) {
            sv[i] += __shfl_xor(sv[i], off);
            dv[i] += __shfl_xor(dv[i], off);
        }
    }
    if (c16 == 0) {
        int hb = (H == 4) ? (n0 >> 7) : 0;
#pragma unroll
        for (int mt = 0; mt < 4; ++mt) {
#pragma unroll
            for (int r = 0; r < 4; ++r) {
                int row = m0 + wm + mt * 16 + quad * 4 + r;
                if (row < M) {
                    atomicAdd(&s_log[row * H + hb], sv[mt * 4 + r]);
                    atomicAdd(&d_log[row * H + hb], dv[mt * 4 + r]);
                }
            }
        }
    }
}

// ---------------------------------------------------------------------------
// FUSED edge softmax + weighted gather-aggregate. One wave per dst node
// (4 waves / 256-thr block). Phase 1-2: scalar softmax over the node's edge
// list (max, then exp-weights written to ew + z-sum), wself/zinv stay in
// registers. Phase 3: the aggregate3 gather (uint4 1KB-row loads).
// ---------------------------------------------------------------------------
__device__ __forceinline__ void acc8(float* acc, uint4 q, float w) {
    acc[0] += w * bf_lo(q.x); acc[1] += w * bf_hi(q.x);
    acc[2] += w * bf_lo(q.y); acc[3] += w * bf_hi(q.y);
    acc[4] += w * bf_lo(q.z); acc[5] += w * bf_hi(q.z);
    acc[6] += w * bf_lo(q.w); acc[7] += w * bf_hi(q.w);
}

template<int H>
__global__ __launch_bounds__(256) void softagg_kernel(
    const uint4* __restrict__ xpb4,     // [node][64] (512 bf16 / row)
    const float* __restrict__ s,        // [node][H]
    const float* __restrict__ dlog,     // [node][H]
    const int* __restrict__ offsets, const int* __restrict__ esrc,
    float* __restrict__ ew,             // [E][H] scratch
    const float* __restrict__ bias,     // [OUTC]
    float* __restrict__ out,            // [node][ldo]
    int OUTC, int ldo)
{
    int node = blockIdx.x * 4 + (threadIdx.x >> 6);
    if (node >= NNODES) return;
    int lane = threadIdx.x & 63;
    int e0 = offsets[node], e1 = offsets[node + 1];

    // ---- softmax phase ----
    float dh[H], selfe[H], mh[H], zh[H];
#pragma unroll
    for (int h = 0; h < H; ++h) {
        dh[h] = dlog[node * H + h];
        selfe[h] = lrelu(s[node * H + h] + dh[h]);
        mh[h] = selfe[h];
        zh[h] = 0.f;
    }
    for (int j = e0 + lane; j < e1; j += 64) {
        int src = esrc[j];
        if (H == 4) {
            float4 sv = ((const float4*)s)[src];
            mh[0] = fmaxf(mh[0], lrelu(sv.x + dh[0]));
            mh[1] = fmaxf(mh[1], lrelu(sv.y + dh[1]));
            mh[2] = fmaxf(mh[2], lrelu(sv.z + dh[2]));
            mh[3] = fmaxf(mh[3], lrelu(sv.w + dh[3]));
        } else {
#pragma unroll
            for (int h = 0; h < H; ++h)
                mh[h] = fmaxf(mh[h], lrelu(s[src * H + h] + dh[h]));
        }
    }
#pragma unroll
    for (int h = 0; h < H; ++h)
        for (int off = 32; off > 0; off >>= 1)
            mh[h] = fmaxf(mh[h], __shfl_xor(mh[h], off));

    for (int j = e0 + lane; j < e1; j += 64) {
        int src = esrc[j];
        if (H == 4) {
            float4 sv = ((const float4*)s)[src];
            float w0 = __expf(lrelu(sv.x + dh[0]) - mh[0]);
            float w1 = __expf(lrelu(sv.y + dh[1]) - mh[1]);
            float w2 = __expf(lrelu(sv.z + dh[2]) - mh[2]);
            float w3 = __expf(lrelu(sv.w + dh[3]) - mh[3]);
            ((float4*)ew)[j] = make_float4(w0, w1, w2, w3);
            zh[0] += w0; zh[1] += w1; zh[2] += w2; zh[3] += w3;
        } else {
#pragma unroll
            for (int h = 0; h < H; ++h) {
                float w = __expf(lrelu(s[src * H + h] + dh[h]) - mh[h]);
                ew[(size_t)j * H + h] = w;
                zh[h] += w;
            }
        }
    }
#pragma unroll
    for (int h = 0; h < H; ++h)
        for (int off = 32; off > 0; off >>= 1)
            zh[h] += __shfl_xor(zh[h], off);

    float ws_[H], zi_[H];
#pragma unroll
    for (int h = 0; h < H; ++h) {
        ws_[h] = __expf(selfe[h] - mh[h]);
        zi_[h] = 1.0f / (zh[h] + ws_[h]);
    }
    int hg = (H == 4) ? (lane >> 4) : 0;
    float ws, zi;
    if (H == 4) {
        ws = (hg == 0) ? ws_[0] : (hg == 1) ? ws_[1] : (hg == 2) ? ws_[2] : ws_[3];
        zi = (hg == 0) ? zi_[0] : (hg == 1) ? zi_[1] : (hg == 2) ? zi_[2] : zi_[3];
    } else { ws = ws_[0]; zi = zi_[0]; }

    // ---- gather phase ----
    uint4 p = xpb4[(size_t)node * 64 + lane];
    float acc[8];
    acc[0] = ws * bf_lo(p.x); acc[1] = ws * bf_hi(p.x);
    acc[2] = ws * bf_lo(p.y); acc[3] = ws * bf_hi(p.y);
    acc[4] = ws * bf_lo(p.z); acc[5] = ws * bf_hi(p.z);
    acc[6] = ws * bf_lo(p.w); acc[7] = ws * bf_hi(p.w);

    int j = e0;
    for (; j + 3 < e1; j += 4) {
        int s0 = esrc[j], s1 = esrc[j + 1], s2 = esrc[j + 2], s3 = esrc[j + 3];
        float w0 = ew[(size_t)j * H + hg];
        float w1 = ew[(size_t)(j + 1) * H + hg];
        float w2 = ew[(size_t)(j + 2) * H + hg];
        float w3 = ew[(size_t)(j + 3) * H + hg];
        uint4 q0 = xpb4[(size_t)s0 * 64 + lane];
        uint4 q1 = xpb4[(size_t)s1 * 64 + lane];
        uint4 q2 = xpb4[(size_t)s2 * 64 + lane];
        uint4 q3 = xpb4[(size_t)s3 * 64 + lane];
        acc8(acc, q0, w0);
        acc8(acc, q1, w1);
        acc8(acc, q2, w2);
        acc8(acc, q3, w3);
    }
    for (; j < e1; ++j) {
        int s0 = esrc[j];
        float w0 = ew[(size_t)j * H + hg];
        uint4 q0 = xpb4[(size_t)s0 * 64 + lane];
        acc8(acc, q0, w0);
    }

    int cbase = lane * 8;
    size_t ob = (size_t)node * ldo + cbase;
    if (cbase + 7 < OUTC) {
        float4 o0 = make_float4(acc[0] * zi + bias[cbase + 0], acc[1] * zi + bias[cbase + 1],
                                acc[2] * zi + bias[cbase + 2], acc[3] * zi + bias[cbase + 3]);
        float4 o1 = make_float4(acc[4] * zi + bias[cbase + 4], acc[5] * zi + bias[cbase + 5],
                                acc[6] * zi + bias[cbase + 6], acc[7] * zi + bias[cbase + 7]);
        *(float4*)(out + ob) = o0;
        *(float4*)(out + ob + 4) = o1;
    } else {
#pragma unroll
        for (int k = 0; k < 8; ++k) {
            int c = cbase + k;
            if (c < OUTC) out[ob + k] = acc[k] * zi + bias[c];
        }
    }
}

// ---------------------------------------------------------------------------
// BatchNorm: stats (64-block partials) then fused finalize+apply+ELU+pack,
// which also zeroes the next layer's s_log/d_log (folds a dispatch).
// ---------------------------------------------------------------------------
__global__ __launch_bounds__(512) void bn_stats_kernel(const float* __restrict__ h,
                                                       float* __restrict__ psum,
                                                       float* __restrict__ psumsq,
                                                       int Nrows) {
    int c = threadIdx.x;  // 512
    int b = blockIdx.x;   // 64
    float sm = 0.f, sq = 0.f;
    for (int r = b; r < Nrows; r += 64) {
        float v = h[(size_t)r * 512 + c];
        sm += v;
        sq += v * v;
    }
    psum[b * 512 + c] = sm;
    psumsq[b * 512 + c] = sq;
}

__global__ __launch_bounds__(256) void bn_apply2_kernel(const float* __restrict__ h,
                                                        const float* __restrict__ psum,
                                                        const float* __restrict__ psumsq,
                                                        const float* __restrict__ gamma,
                                                        const float* __restrict__ beta,
                                                        uint_t* __restrict__ hbf,
                                                        float* __restrict__ zptr, int zcount) {
    int t = threadIdx.x, b = blockIdx.x;   // grid = 128
    // fold: zero next layer's logit accumulators
    for (int i = b * 256 + t; i < zcount; i += 128 * 256) zptr[i] = 0.f;

    int c0 = t * 2, c1 = c0 + 1;
    float sm0 = 0.f, sq0 = 0.f, sm1 = 0.f, sq1 = 0.f;
    for (int k = 0; k < 64; ++k) {
        sm0 += psum[k * 512 + c0];  sq0 += psumsq[k * 512 + c0];
        sm1 += psum[k * 512 + c1];  sq1 += psumsq[k * 512 + c1];
    }
    const float invN = 1.0f / (float)NNODES;
    float mu0 = sm0 * invN, var0 = sq0 * invN - mu0 * mu0;
    float mu1 = sm1 * invN, var1 = sq1 * invN - mu1 * mu1;
    float sc0 = gamma[c0] * rsqrtf(var0 + BN_EPS);
    float sc1 = gamma[c1] * rsqrtf(var1 + BN_EPS);
    float sh0 = beta[c0] - mu0 * sc0;
    float sh1 = beta[c1] - mu1 * sc1;

    for (int r = b; r < NNODES; r += 128) {
        float2 hv = ((const float2*)(h + (size_t)r * 512))[t];
        float v0 = hv.x * sc0 + sh0;
        float v1 = hv.y * sc1 + sh1;
        v0 = (v0 > 0.f) ? v0 : (__expf(v0) - 1.0f);
        v1 = (v1 > 0.f) ? v1 : (__expf(v1) - 1.0f);
        hbf[r * 256 + t] = ((uint_t)f2bf(v1) << 16) | (uint_t)f2bf(v0);
    }
}

// ---------------------------------------------------------------------------
// launch — 16 dispatches total (was 27)
// ---------------------------------------------------------------------------
extern "C" void kernel_launch(void* const* d_in, const int* in_sizes, int n_in,
                              void* d_out, int out_size, void* d_ws, size_t ws_size,
                              hipStream_t stream) {
    const float* x      = (const float*)d_in[0];
    const int*   ei     = (const int*)d_in[1];
    const float* W1     = (const float*)d_in[2];
    const float* a_src1 = (const float*)d_in[3];
    const float* a_dst1 = (const float*)d_in[4];
    const float* b1     = (const float*)d_in[5];
    const float* g1     = (const float*)d_in[6];
    const float* be1    = (const float*)d_in[7];
    const float* W2     = (const float*)d_in[8];
    const float* a_src2 = (const float*)d_in[9];
    const float* a_dst2 = (const float*)d_in[10];
    const float* b2     = (const float*)d_in[11];
    const float* g2     = (const float*)d_in[12];
    const float* be2    = (const float*)d_in[13];
    const float* W3     = (const float*)d_in[14];
    const float* a_src3 = (const float*)d_in[15];
    const float* a_dst3 = (const float*)d_in[16];
    const float* b3     = (const float*)d_in[17];
    float* out = (float*)d_out;

    const int* e_src = ei;           // edge_index[0]
    const int* e_dst = ei + NEDGES;  // edge_index[1]

    // ---- workspace layout ----
    char* w = (char*)d_ws;
    ushort_t* x_bf = (ushort_t*)w;
    float*    hbuf = (float*)w;                               // alias after L1 GEMM
    float*    ew   = (float*)(w + (size_t)NNODES * HC_ * sizeof(float));  // tail 5.12 MB
    w += (size_t)NNODES * INF_ * sizeof(ushort_t);            // 25,600,000
    uint_t* xpb = (uint_t*)w;  w += (size_t)NNODES * HC_ * sizeof(ushort_t);
    uint_t* hbf = (uint_t*)w;  w += (size_t)NNODES * HC_ * sizeof(ushort_t);
    ushort_t* Wt1 = (ushort_t*)w; w += (size_t)HC_ * INF_ * sizeof(ushort_t);
    ushort_t* Wt2 = (ushort_t*)w; w += (size_t)HC_ * HC_ * sizeof(ushort_t);
    ushort_t* Wt3 = (ushort_t*)w; w += (size_t)HC_ * HC_ * sizeof(ushort_t);
    // counts | s_log | d_log contiguous -> single zero pass
    int* counts  = (int*)w;    w += NNODES * sizeof(int);
    float* s_log = (float*)w;  w += NNODES * HEADS_ * sizeof(float);
    float* d_log = (float*)w;  w += NNODES * HEADS_ * sizeof(float);
    float* bnscale = (float*)w; w += HC_ * sizeof(float);   // (unused slot kept)
    float* psum  = (float*)w;  w += 64 * HC_ * sizeof(float);
    float* psumsq= (float*)w;  w += 64 * HC_ * sizeof(float);
    int* offsets = (int*)w;    w += (NNODES + 1) * sizeof(int);
    int* cursor  = (int*)w;    w += NNODES * sizeof(int);
    int* esrc    = (int*)w;    w += NEDGES * sizeof(int);
    int* bsum    = (int*)w;    w += 64 * sizeof(int);
    (void)bnscale;

    const int nMB = (NNODES + 127) / 128;            // 79
    const int gemmBlocks = ((nMB + 7) / 8) * 64;     // 640
    const int aggGrid = (NNODES + 3) / 4;            // 2500
    const int scanBlocks = (NNODES + 255) / 256;     // 40

    // 1: zero counts + s_log + d_log (contiguous)
    zero_kernel<<<64, 256, 0, stream>>>((float*)counts, NNODES + 2 * NNODES * HEADS_);
    // 2-5: CSR
    count_kernel<<<(NEDGES + 255) / 256, 256, 0, stream>>>(e_dst, counts, NEDGES);
    scan1_kernel<<<scanBlocks, 256, 0, stream>>>(counts, offsets, bsum, NNODES);
    scan3b_kernel<<<scanBlocks, 256, 0, stream>>>(offsets, cursor, bsum, scanBlocks, NNODES);
    scatter_kernel<<<(NEDGES + 255) / 256, 256, 0, stream>>>(e_src, e_dst, cursor, esrc, NEDGES);
    // 6: all dtype conversions in one kernel
    {
        int TOT = CNX + CN1 + CN2 + CN3;
        convall_kernel<<<(TOT + 255) / 256, 256, 0, stream>>>(x, W1, W2, W3, x_bf, Wt1, Wt2, Wt3);
    }

    // ---- Layer 1 (4 dispatches) ----
    gemm_fused_kernel<<<gemmBlocks, 256, 0, stream>>>(x_bf, Wt1, (ushort_t*)xpb,
        a_src1, a_dst1, s_log, d_log, NNODES, INF_, HC_, HEADS_, nMB);
    softagg_kernel<HEADS_><<<aggGrid, 256, 0, stream>>>((const uint4*)xpb, s_log, d_log,
        offsets, esrc, ew, b1, hbuf, HC_, HC_);
    bn_stats_kernel<<<64, 512, 0, stream>>>(hbuf, psum, psumsq, NNODES);
    bn_apply2_kernel<<<128, 256, 0, stream>>>(hbuf, psum, psumsq, g1, be1, hbf,
        s_log, 2 * NNODES * HEADS_);   // zeroes s_log+d_log for L2

    // ---- Layer 2 (4 dispatches) ----
    gemm_fused_kernel<<<gemmBlocks, 256, 0, stream>>>((const ushort_t*)hbf, Wt2, (ushort_t*)xpb,
        a_src2, a_dst2, s_log, d_log, NNODES, HC_, HC_, HEADS_, nMB);
    softagg_kernel<HEADS_><<<aggGrid, 256, 0, stream>>>((const uint4*)xpb, s_log, d_log,
        offsets, esrc, ew, b2, hbuf, HC_, HC_);
    bn_stats_kernel<<<64, 512, 0, stream>>>(hbuf, psum, psumsq, NNODES);
    bn_apply2_kernel<<<128, 256, 0, stream>>>(hbuf, psum, psumsq, g2, be2, hbf,
        s_log, 2 * NNODES * HEADS_);   // zeroes s_log+d_log for L3

    // ---- Layer 3 (2 dispatches; H=1, N=500) ----
    gemm_fused_kernel<<<gemmBlocks, 256, 0, stream>>>((const ushort_t*)hbf, Wt3, (ushort_t*)xpb,
        a_src3, a_dst3, s_log, d_log, NNODES, HC_, OUTF_, 1, nMB);
    softagg_kernel<1><<<aggGrid, 256, 0, stream>>>((const uint4*)xpb, s_log, d_log,
        offsets, esrc, ew, b3, out, OUTF_, OUTF_);
}

// Round 9
// 523.872 us; speedup vs baseline: 1.0567x; 1.0298x over previous
//
#include <hip/hip_runtime.h>
#include <hip/hip_bf16.h>

// Problem constants (from reference)
#define NNODES 10000
#define NEDGES 320000
#define INF_   1280
#define HID_   128
#define HEADS_ 4
#define OUTF_  500
#define HC_    512          // HEADS_*HID_
#define NEG_SLOPE 0.2f
#define BN_EPS 1e-5f

typedef __attribute__((ext_vector_type(8))) short short8x;
typedef __attribute__((ext_vector_type(4))) float f32x4;
typedef unsigned short ushort_t;
typedef unsigned int uint_t;

__device__ __forceinline__ ushort_t f2bf(float f) {
    uint_t u = __float_as_uint(f);
    u = (u + 0x7fffu + ((u >> 16) & 1u)) >> 16;   // round-to-nearest-even
    return (ushort_t)u;
}
__device__ __forceinline__ float bf_lo(uint_t p) { return __uint_as_float(p << 16); }
__device__ __forceinline__ float bf_hi(uint_t p) { return __uint_as_float(p & 0xffff0000u); }
__device__ __forceinline__ float lrelu(float x) { return (x >= 0.f) ? x : NEG_SLOPE * x; }

// ---------------------------------------------------------------------------
// utility
// ---------------------------------------------------------------------------
__global__ void zero_kernel(float* __restrict__ p, size_t n) {
    size_t i = (size_t)blockIdx.x * blockDim.x + threadIdx.x;
    size_t stride = (size_t)gridDim.x * blockDim.x;
    for (; i < n; i += stride) p[i] = 0.0f;
}

// weights only now (x is consumed fp32 by the L1 GEMM directly)
#define CN1 (HC_ * INF_)               // Wt1: 512 rows x 1280
#define CN2 (HC_ * HC_)                // Wt2
#define CN3 (HC_ * HC_)                // Wt3 (padded rows)
__global__ void convW_kernel(const float* __restrict__ W1,
                             const float* __restrict__ W2,
                             const float* __restrict__ W3,
                             ushort_t* __restrict__ Wt1,
                             ushort_t* __restrict__ Wt2,
                             ushort_t* __restrict__ Wt3) {
    int i = blockIdx.x * blockDim.x + threadIdx.x;
    if (i < CN1) {
        int n = i / INF_, k = i - n * INF_;
        Wt1[i] = f2bf(W1[(size_t)k * HC_ + n]);
    } else if (i < CN1 + CN2) {
        int j = i - CN1;
        int n = j / HC_, k = j - n * HC_;
        Wt2[j] = f2bf(W2[(size_t)k * HC_ + n]);
    } else if (i < CN1 + CN2 + CN3) {
        int j = i - CN1 - CN2;
        int n = j / HC_, k = j - n * HC_;
        Wt3[j] = (n < OUTF_) ? f2bf(W3[(size_t)k * OUTF_ + n]) : (ushort_t)0;
    }
}

// ---------------------------------------------------------------------------
// CSR build (by destination)
// ---------------------------------------------------------------------------
__global__ void count_kernel(const int* __restrict__ dst, int* __restrict__ counts, int E) {
    int e = blockIdx.x * blockDim.x + threadIdx.x;
    if (e < E) atomicAdd(&counts[dst[e]], 1);
}

__global__ __launch_bounds__(256) void scan1_kernel(const int* __restrict__ counts,
                                                    int* __restrict__ offsets,
                                                    int* __restrict__ bsum, int n) {
    __shared__ int tmp[256];
    int b = blockIdx.x, t = threadIdx.x;
    int i = b * 256 + t;
    int v = (i < n) ? counts[i] : 0;
    tmp[t] = v;
    __syncthreads();
    for (int off = 1; off < 256; off <<= 1) {
        int u = (t >= off) ? tmp[t - off] : 0;
        __syncthreads();
        tmp[t] += u;
        __syncthreads();
    }
    if (i < n) offsets[i] = tmp[t] - v;
    if (t == 255) bsum[b] = tmp[t];
}

__global__ __launch_bounds__(256) void scan3b_kernel(int* __restrict__ offsets,
                                                     int* __restrict__ cursor,
                                                     const int* __restrict__ bsum,
                                                     int nb, int n) {
    __shared__ int base_sh, tot_sh;
    int b = blockIdx.x, t = threadIdx.x;
    if (t == 0) {
        int acc = 0, tot = 0;
        for (int k = 0; k < nb; ++k) { if (k < b) acc += bsum[k]; tot += bsum[k]; }
        base_sh = acc; tot_sh = tot;
    }
    __syncthreads();
    int i = b * 256 + t;
    if (i < n) {
        int v = offsets[i] + base_sh;
        offsets[i] = v;
        cursor[i] = v;
    }
    if (b == nb - 1 && t == 0) offsets[n] = tot_sh;
}

__global__ void scatter_kernel(const int* __restrict__ src, const int* __restrict__ dst,
                               int* __restrict__ cursor, int* __restrict__ esrc, int E) {
    int e = blockIdx.x * blockDim.x + threadIdx.x;
    if (e < E) {
        int p = atomicAdd(&cursor[dst[e]], 1);
        esrc[p] = src[e];
    }
}

// ---------------------------------------------------------------------------
// bf16 MFMA GEMM with fused attention-logit epilogue.
//   AF32: A is fp32 and converted to bf16 during LDS staging (saves a whole
//   convert pass over x: 51 MB read + 25.6 MB write + 25.6 MB re-read).
//   Tile 128x64, BK=64, 256 thr = 4 waves (64x32 each, 16 MFMAs/barrier).
//   XCD-swizzled 1-D grid (keeps A L2-resident; FETCH 100->17.7 MB in R6).
// ---------------------------------------------------------------------------
#define LDTK 72

template<bool AF32>
__global__ __launch_bounds__(256) void gemm_fused_kernel(
    const void* __restrict__ Araw,     // [M][K] bf16 or fp32
    const ushort_t* __restrict__ Bt,   // [512][K] bf16 (transposed, padded)
    ushort_t* __restrict__ Cb,         // [M][512] bf16
    const float* __restrict__ avS,     // a_src flat [N]
    const float* __restrict__ avD,     // a_dst flat [N]
    float* __restrict__ s_log,         // [M][H] (pre-zeroed)
    float* __restrict__ d_log,         // [M][H]
    int M, int K, int N, int H, int nMB)
{
    __shared__ __align__(16) ushort_t As[128 * LDTK];
    __shared__ __align__(16) ushort_t Bs[64 * LDTK];

    int id = blockIdx.x;
    int mb = (id >> 6) * 8 + (id & 7);
    int nb = (id >> 3) & 7;
    if (mb >= nMB) return;
    int m0 = mb * 128, n0 = nb * 64;

    int tid  = threadIdx.x;
    int lane = tid & 63;
    int w    = tid >> 6;
    int wm   = (w & 1) * 64;
    int wn   = (w >> 1) * 32;
    int quad = lane >> 4;
    int c16  = lane & 15;

    f32x4 acc[4][2];
#pragma unroll
    for (int i = 0; i < 4; ++i)
#pragma unroll
        for (int j = 0; j < 2; ++j)
#pragma unroll
            for (int r = 0; r < 4; ++r) acc[i][j][r] = 0.0f;

    for (int k0 = 0; k0 < K; k0 += 64) {
        if (AF32) {
            const float* A = (const float*)Araw;
            // A tile 128x64 fp32: 2048 float4 chunks / 256 thr = 8 per thread
#pragma unroll
            for (int t = 0; t < 8; ++t) {
                int ci = t * 256 + tid;
                int row = ci >> 4;            // 16 float4s per row
                int c4 = (ci & 15) * 4;
                int gm = m0 + row;
                if (gm > M - 1) gm = M - 1;
                float4 av = *(const float4*)(A + (size_t)gm * K + k0 + c4);
                uint_t p0 = ((uint_t)f2bf(av.y) << 16) | (uint_t)f2bf(av.x);
                uint_t p1 = ((uint_t)f2bf(av.w) << 16) | (uint_t)f2bf(av.z);
                *(uint2*)&As[row * LDTK + c4] = make_uint2(p0, p1);
            }
        } else {
            const ushort_t* A = (const ushort_t*)Araw;
#pragma unroll
            for (int t = 0; t < 4; ++t) {
                int ci = t * 256 + tid;
                int row = ci >> 3;
                int kc = (ci & 7) * 8;
                int gm = m0 + row;
                if (gm > M - 1) gm = M - 1;
                uint4 av = *(const uint4*)(A + (size_t)gm * K + k0 + kc);
                *(uint4*)&As[row * LDTK + kc] = av;
            }
        }
#pragma unroll
        for (int t = 0; t < 2; ++t) {
            int ci = t * 256 + tid;
            int row = ci >> 3;
            int kc = (ci & 7) * 8;
            uint4 bv = *(const uint4*)(Bt + (size_t)(n0 + row) * K + k0 + kc);
            *(uint4*)&Bs[row * LDTK + kc] = bv;
        }
        __syncthreads();

#pragma unroll
        for (int ks = 0; ks < 2; ++ks) {
            short8x af[4], bf[2];
#pragma unroll
            for (int mt = 0; mt < 4; ++mt)
                af[mt] = *(const short8x*)&As[(wm + mt * 16 + c16) * LDTK + ks * 32 + quad * 8];
#pragma unroll
            for (int nt = 0; nt < 2; ++nt)
                bf[nt] = *(const short8x*)&Bs[(wn + nt * 16 + c16) * LDTK + ks * 32 + quad * 8];
#pragma unroll
            for (int mt = 0; mt < 4; ++mt)
#pragma unroll
                for (int nt = 0; nt < 2; ++nt)
                    acc[mt][nt] = __builtin_amdgcn_mfma_f32_16x16x32_bf16(
                        af[mt], bf[nt], acc[mt][nt], 0, 0, 0);
        }
        __syncthreads();
    }

    int col0 = n0 + wn + c16;
    int col1 = col0 + 16;
    float as0 = (col0 < N) ? avS[col0] : 0.f;
    float as1 = (col1 < N) ? avS[col1] : 0.f;
    float ad0 = (col0 < N) ? avD[col0] : 0.f;
    float ad1 = (col1 < N) ? avD[col1] : 0.f;

    float sv[16], dv[16];
#pragma unroll
    for (int mt = 0; mt < 4; ++mt) {
#pragma unroll
        for (int r = 0; r < 4; ++r) {
            float v0 = acc[mt][0][r];
            float v1 = acc[mt][1][r];
            sv[mt * 4 + r] = v0 * as0 + v1 * as1;
            dv[mt * 4 + r] = v0 * ad0 + v1 * ad1;
            int row = m0 + wm + mt * 16 + quad * 4 + r;
            if (row < M) {
                Cb[(size_t)row * 512 + col0] = f2bf(v0);
                Cb[(size_t)row * 512 + col1] = f2bf(v1);
            }
        }
    }
#pragma unroll
    for (int off = 1; off < 16; off <<= 1) {
#pragma unroll
        for (int i = 0; i < 16; ++i) {
            sv[i] += __shfl_xor(sv[i], off);
            dv[i] += __shfl_xor(dv[i], off);
        }
    }
    if (c16 == 0) {
        int hb = (H == 4) ? (n0 >> 7) : 0;
#pragma unroll
        for (int mt = 0; mt < 4; ++mt) {
#pragma unroll
            for (int r = 0; r < 4; ++r) {
                int row = m0 + wm + mt * 16 + quad * 4 + r;
                if (row < M) {
                    atomicAdd(&s_log[row * H + hb], sv[mt * 4 + r]);
                    atomicAdd(&d_log[row * H + hb], dv[mt * 4 + r]);
                }
            }
        }
    }
}

// ---------------------------------------------------------------------------
// FUSED edge softmax + weighted gather-aggregate (wave-per-node, 8-deep MLP).
// ---------------------------------------------------------------------------
__device__ __forceinline__ void acc8(float* acc, uint4 q, float w) {
    acc[0] += w * bf_lo(q.x); acc[1] += w * bf_hi(q.x);
    acc[2] += w * bf_lo(q.y); acc[3] += w * bf_hi(q.y);
    acc[4] += w * bf_lo(q.z); acc[5] += w * bf_hi(q.z);
    acc[6] += w * bf_lo(q.w); acc[7] += w * bf_hi(q.w);
}

template<int H>
__global__ __launch_bounds__(256) void softagg_kernel(
    const uint4* __restrict__ xpb4,     // [node][64] (512 bf16 / row)
    const float* __restrict__ s,        // [node][H]
    const float* __restrict__ dlog,     // [node][H]
    const int* __restrict__ offsets, const int* __restrict__ esrc,
    float* __restrict__ ew,             // [E][H] scratch
    const float* __restrict__ bias,     // [OUTC]
    float* __restrict__ out,            // [node][ldo]
    int OUTC, int ldo)
{
    int node = blockIdx.x * 4 + (threadIdx.x >> 6);
    if (node >= NNODES) return;
    int lane = threadIdx.x & 63;
    int e0 = offsets[node], e1 = offsets[node + 1];

    // ---- softmax phase ----
    float dh[H], selfe[H], mh[H], zh[H];
#pragma unroll
    for (int h = 0; h < H; ++h) {
        dh[h] = dlog[node * H + h];
        selfe[h] = lrelu(s[node * H + h] + dh[h]);
        mh[h] = selfe[h];
        zh[h] = 0.f;
    }
    for (int j = e0 + lane; j < e1; j += 64) {
        int src = esrc[j];
        if (H == 4) {
            float4 sv = ((const float4*)s)[src];
            mh[0] = fmaxf(mh[0], lrelu(sv.x + dh[0]));
            mh[1] = fmaxf(mh[1], lrelu(sv.y + dh[1]));
            mh[2] = fmaxf(mh[2], lrelu(sv.z + dh[2]));
            mh[3] = fmaxf(mh[3], lrelu(sv.w + dh[3]));
        } else {
#pragma unroll
            for (int h = 0; h < H; ++h)
                mh[h] = fmaxf(mh[h], lrelu(s[src * H + h] + dh[h]));
        }
    }
#pragma unroll
    for (int h = 0; h < H; ++h)
        for (int off = 32; off > 0; off >>= 1)
            mh[h] = fmaxf(mh[h], __shfl_xor(mh[h], off));

    for (int j = e0 + lane; j < e1; j += 64) {
        int src = esrc[j];
        if (H == 4) {
            float4 sv = ((const float4*)s)[src];
            float w0 = __expf(lrelu(sv.x + dh[0]) - mh[0]);
            float w1 = __expf(lrelu(sv.y + dh[1]) - mh[1]);
            float w2 = __expf(lrelu(sv.z + dh[2]) - mh[2]);
            float w3 = __expf(lrelu(sv.w + dh[3]) - mh[3]);
            ((float4*)ew)[j] = make_float4(w0, w1, w2, w3);
            zh[0] += w0; zh[1] += w1; zh[2] += w2; zh[3] += w3;
        } else {
#pragma unroll
            for (int h = 0; h < H; ++h) {
                float w = __expf(lrelu(s[src * H + h] + dh[h]) - mh[h]);
                ew[(size_t)j * H + h] = w;
                zh[h] += w;
            }
        }
    }
#pragma unroll
    for (int h = 0; h < H; ++h)
        for (int off = 32; off > 0; off >>= 1)
            zh[h] += __shfl_xor(zh[h], off);

    float ws_[H], zi_[H];
#pragma unroll
    for (int h = 0; h < H; ++h) {
        ws_[h] = __expf(selfe[h] - mh[h]);
        zi_[h] = 1.0f / (zh[h] + ws_[h]);
    }
    int hg = (H == 4) ? (lane >> 4) : 0;
    float ws, zi;
    if (H == 4) {
        ws = (hg == 0) ? ws_[0] : (hg == 1) ? ws_[1] : (hg == 2) ? ws_[2] : ws_[3];
        zi = (hg == 0) ? zi_[0] : (hg == 1) ? zi_[1] : (hg == 2) ? zi_[2] : zi_[3];
    } else { ws = ws_[0]; zi = zi_[0]; }

    // ---- gather phase (8-deep) ----
    uint4 p = xpb4[(size_t)node * 64 + lane];
    float acc[8];
    acc[0] = ws * bf_lo(p.x); acc[1] = ws * bf_hi(p.x);
    acc[2] = ws * bf_lo(p.y); acc[3] = ws * bf_hi(p.y);
    acc[4] = ws * bf_lo(p.z); acc[5] = ws * bf_hi(p.z);
    acc[6] = ws * bf_lo(p.w); acc[7] = ws * bf_hi(p.w);

    int j = e0;
    for (; j + 7 < e1; j += 8) {
        int ss[8]; float ww[8]; uint4 qq[8];
#pragma unroll
        for (int t = 0; t < 8; ++t) ss[t] = esrc[j + t];
#pragma unroll
        for (int t = 0; t < 8; ++t) ww[t] = ew[(size_t)(j + t) * H + hg];
#pragma unroll
        for (int t = 0; t < 8; ++t) qq[t] = xpb4[(size_t)ss[t] * 64 + lane];
#pragma unroll
        for (int t = 0; t < 8; ++t) acc8(acc, qq[t], ww[t]);
    }
    for (; j + 3 < e1; j += 4) {
        int s0 = esrc[j], s1 = esrc[j + 1], s2 = esrc[j + 2], s3 = esrc[j + 3];
        float w0 = ew[(size_t)j * H + hg];
        float w1 = ew[(size_t)(j + 1) * H + hg];
        float w2 = ew[(size_t)(j + 2) * H + hg];
        float w3 = ew[(size_t)(j + 3) * H + hg];
        uint4 q0 = xpb4[(size_t)s0 * 64 + lane];
        uint4 q1 = xpb4[(size_t)s1 * 64 + lane];
        uint4 q2 = xpb4[(size_t)s2 * 64 + lane];
        uint4 q3 = xpb4[(size_t)s3 * 64 + lane];
        acc8(acc, q0, w0);
        acc8(acc, q1, w1);
        acc8(acc, q2, w2);
        acc8(acc, q3, w3);
    }
    for (; j < e1; ++j) {
        int s0 = esrc[j];
        float w0 = ew[(size_t)j * H + hg];
        uint4 q0 = xpb4[(size_t)s0 * 64 + lane];
        acc8(acc, q0, w0);
    }

    int cbase = lane * 8;
    size_t ob = (size_t)node * ldo + cbase;
    if (cbase + 7 < OUTC) {
        float4 o0 = make_float4(acc[0] * zi + bias[cbase + 0], acc[1] * zi + bias[cbase + 1],
                                acc[2] * zi + bias[cbase + 2], acc[3] * zi + bias[cbase + 3]);
        float4 o1 = make_float4(acc[4] * zi + bias[cbase + 4], acc[5] * zi + bias[cbase + 5],
                                acc[6] * zi + bias[cbase + 6], acc[7] * zi + bias[cbase + 7]);
        *(float4*)(out + ob) = o0;
        *(float4*)(out + ob + 4) = o1;
    } else {
#pragma unroll
        for (int k = 0; k < 8; ++k) {
            int c = cbase + k;
            if (c < OUTC) out[ob + k] = acc[k] * zi + bias[c];
        }
    }
}

// ---------------------------------------------------------------------------
// BatchNorm: stats (64-block partials, folds next-layer logit zeroing) ->
// tiny finalize (scale/shift) -> wide apply+ELU+pack.
// ---------------------------------------------------------------------------
__global__ __launch_bounds__(512) void bn_stats_kernel(const float* __restrict__ h,
                                                       float* __restrict__ psum,
                                                       float* __restrict__ psumsq,
                                                       float* __restrict__ zptr, int zcount) {
    int c = threadIdx.x;  // 512
    int b = blockIdx.x;   // 64
    for (int i = b * 512 + c; i < zcount; i += 64 * 512) zptr[i] = 0.f;
    float sm = 0.f, sq = 0.f;
    for (int r = b; r < NNODES; r += 64) {
        float v = h[(size_t)r * 512 + c];
        sm += v;
        sq += v * v;
    }
    psum[b * 512 + c] = sm;
    psumsq[b * 512 + c] = sq;
}

__global__ __launch_bounds__(512) void bn_finalize_kernel(const float* __restrict__ psum,
                                                          const float* __restrict__ psumsq,
                                                          const float* __restrict__ gamma,
                                                          const float* __restrict__ beta,
                                                          float* __restrict__ scale,
                                                          float* __restrict__ shift) {
    int c = threadIdx.x;
    float sm = 0.f, sq = 0.f;
    for (int b = 0; b < 64; ++b) {
        sm += psum[b * 512 + c];
        sq += psumsq[b * 512 + c];
    }
    const float invN = 1.0f / (float)NNODES;
    float mu = sm * invN;
    float var = sq * invN - mu * mu;
    float sc = gamma[c] * rsqrtf(var + BN_EPS);
    scale[c] = sc;
    shift[c] = beta[c] - mu * sc;
}

__global__ __launch_bounds__(256) void bn_apply_kernel(const float* __restrict__ h,
                                                       const float* __restrict__ scale,
                                                       const float* __restrict__ shift,
                                                       uint_t* __restrict__ hbf) {
    int t = threadIdx.x, b = blockIdx.x;   // grid = 256
    int c0 = t * 2, c1 = c0 + 1;
    float sc0 = scale[c0], sc1 = scale[c1];
    float sh0 = shift[c0], sh1 = shift[c1];
    for (int r = b; r < NNODES; r += 256) {
        float2 hv = ((const float2*)(h + (size_t)r * 512))[t];
        float v0 = hv.x * sc0 + sh0;
        float v1 = hv.y * sc1 + sh1;
        v0 = (v0 > 0.f) ? v0 : (__expf(v0) - 1.0f);
        v1 = (v1 > 0.f) ? v1 : (__expf(v1) - 1.0f);
        hbf[r * 256 + t] = ((uint_t)f2bf(v1) << 16) | (uint_t)f2bf(v0);
    }
}

// ---------------------------------------------------------------------------
// launch — 18 dispatches
// ---------------------------------------------------------------------------
extern "C" void kernel_launch(void* const* d_in, const int* in_sizes, int n_in,
                              void* d_out, int out_size, void* d_ws, size_t ws_size,
                              hipStream_t stream) {
    const float* x      = (const float*)d_in[0];
    const int*   ei     = (const int*)d_in[1];
    const float* W1     = (const float*)d_in[2];
    const float* a_src1 = (const float*)d_in[3];
    const float* a_dst1 = (const float*)d_in[4];
    const float* b1     = (const float*)d_in[5];
    const float* g1     = (const float*)d_in[6];
    const float* be1    = (const float*)d_in[7];
    const float* W2     = (const float*)d_in[8];
    const float* a_src2 = (const float*)d_in[9];
    const float* a_dst2 = (const float*)d_in[10];
    const float* b2     = (const float*)d_in[11];
    const float* g2     = (const float*)d_in[12];
    const float* be2    = (const float*)d_in[13];
    const float* W3     = (const float*)d_in[14];
    const float* a_src3 = (const float*)d_in[15];
    const float* a_dst3 = (const float*)d_in[16];
    const float* b3     = (const float*)d_in[17];
    float* out = (float*)d_out;

    const int* e_src = ei;           // edge_index[0]
    const int* e_dst = ei + NEDGES;  // edge_index[1]

    // ---- workspace layout ----
    char* w = (char*)d_ws;
    float*    hbuf = (float*)w;                               // 20.48 MB
    float*    ew   = (float*)(w + (size_t)NNODES * HC_ * sizeof(float));  // 5.12 MB
    w += (size_t)NNODES * INF_ * sizeof(ushort_t);            // 25.6 MB region
    uint_t* xpb = (uint_t*)w;  w += (size_t)NNODES * HC_ * sizeof(ushort_t);
    uint_t* hbf = (uint_t*)w;  w += (size_t)NNODES * HC_ * sizeof(ushort_t);
    ushort_t* Wt1 = (ushort_t*)w; w += (size_t)HC_ * INF_ * sizeof(ushort_t);
    ushort_t* Wt2 = (ushort_t*)w; w += (size_t)HC_ * HC_ * sizeof(ushort_t);
    ushort_t* Wt3 = (ushort_t*)w; w += (size_t)HC_ * HC_ * sizeof(ushort_t);
    // counts | s_log | d_log contiguous -> single zero pass
    int* counts  = (int*)w;    w += NNODES * sizeof(int);
    float* s_log = (float*)w;  w += NNODES * HEADS_ * sizeof(float);
    float* d_log = (float*)w;  w += NNODES * HEADS_ * sizeof(float);
    float* bnscale = (float*)w; w += HC_ * sizeof(float);
    float* bnshift = (float*)w; w += HC_ * sizeof(float);
    float* psum  = (float*)w;  w += 64 * HC_ * sizeof(float);
    float* psumsq= (float*)w;  w += 64 * HC_ * sizeof(float);
    int* offsets = (int*)w;    w += (NNODES + 1) * sizeof(int);
    int* cursor  = (int*)w;    w += NNODES * sizeof(int);
    int* esrc    = (int*)w;    w += NEDGES * sizeof(int);
    int* bsum    = (int*)w;    w += 64 * sizeof(int);

    const int nMB = (NNODES + 127) / 128;            // 79
    const int gemmBlocks = ((nMB + 7) / 8) * 64;     // 640
    const int aggGrid = (NNODES + 3) / 4;            // 2500
    const int scanBlocks = (NNODES + 255) / 256;     // 40

    zero_kernel<<<64, 256, 0, stream>>>((float*)counts, NNODES + 2 * NNODES * HEADS_);
    count_kernel<<<(NEDGES + 255) / 256, 256, 0, stream>>>(e_dst, counts, NEDGES);
    scan1_kernel<<<scanBlocks, 256, 0, stream>>>(counts, offsets, bsum, NNODES);
    scan3b_kernel<<<scanBlocks, 256, 0, stream>>>(offsets, cursor, bsum, scanBlocks, NNODES);
    scatter_kernel<<<(NEDGES + 255) / 256, 256, 0, stream>>>(e_src, e_dst, cursor, esrc, NEDGES);
    {
        int TOT = CN1 + CN2 + CN3;
        convW_kernel<<<(TOT + 255) / 256, 256, 0, stream>>>(W1, W2, W3, Wt1, Wt2, Wt3);
    }

    // ---- Layer 1 (GEMM reads x fp32 directly) ----
    gemm_fused_kernel<true><<<gemmBlocks, 256, 0, stream>>>(x, Wt1, (ushort_t*)xpb,
        a_src1, a_dst1, s_log, d_log, NNODES, INF_, HC_, HEADS_, nMB);
    softagg_kernel<HEADS_><<<aggGrid, 256, 0, stream>>>((const uint4*)xpb, s_log, d_log,
        offsets, esrc, ew, b1, hbuf, HC_, HC_);
    bn_stats_kernel<<<64, 512, 0, stream>>>(hbuf, psum, psumsq, s_log, 2 * NNODES * HEADS_);
    bn_finalize_kernel<<<1, 512, 0, stream>>>(psum, psumsq, g1, be1, bnscale, bnshift);
    bn_apply_kernel<<<256, 256, 0, stream>>>(hbuf, bnscale, bnshift, hbf);

    // ---- Layer 2 ----
    gemm_fused_kernel<false><<<gemmBlocks, 256, 0, stream>>>(hbf, Wt2, (ushort_t*)xpb,
        a_src2, a_dst2, s_log, d_log, NNODES, HC_, HC_, HEADS_, nMB);
    softagg_kernel<HEADS_><<<aggGrid, 256, 0, stream>>>((const uint4*)xpb, s_log, d_log,
        offsets, esrc, ew, b2, hbuf, HC_, HC_);
    bn_stats_kernel<<<64, 512, 0, stream>>>(hbuf, psum, psumsq, s_log, 2 * NNODES * HEADS_);
    bn_finalize_kernel<<<1, 512, 0, stream>>>(psum, psumsq, g2, be2, bnscale, bnshift);
    bn_apply_kernel<<<256, 256, 0, stream>>>(hbuf, bnscale, bnshift, hbf);

    // ---- Layer 3 (H=1, N=500) ----
    gemm_fused_kernel<false><<<gemmBlocks, 256, 0, stream>>>(hbf, Wt3, (ushort_t*)xpb,
        a_src3, a_dst3, s_log, d_log, NNODES, HC_, OUTF_, 1, nMB);
    softagg_kernel<1><<<aggGrid, 256, 0, stream>>>((const uint4*)xpb, s_log, d_log,
        offsets, esrc, ew, b3, out, OUTF_, OUTF_);
}

// Round 10
// 520.802 us; speedup vs baseline: 1.0629x; 1.0059x over previous
//
#include <hip/hip_runtime.h>
#include <hip/hip_bf16.h>

// Problem constants (from reference)
#define NNODES 10000
#define NEDGES 320000
#define INF_   1280
#define HID_   128
#define HEADS_ 4
#define OUTF_  500
#define HC_    512          // HEADS_*HID_
#define NEG_SLOPE 0.2f
#define BN_EPS 1e-5f

typedef __attribute__((ext_vector_type(8))) short short8x;
typedef __attribute__((ext_vector_type(4))) float f32x4;
typedef unsigned short ushort_t;
typedef unsigned int uint_t;

__device__ __forceinline__ ushort_t f2bf(float f) {
    uint_t u = __float_as_uint(f);
    u = (u + 0x7fffu + ((u >> 16) & 1u)) >> 16;   // round-to-nearest-even
    return (ushort_t)u;
}
__device__ __forceinline__ float bf_lo(uint_t p) { return __uint_as_float(p << 16); }
__device__ __forceinline__ float bf_hi(uint_t p) { return __uint_as_float(p & 0xffff0000u); }
__device__ __forceinline__ float lrelu(float x) { return (x >= 0.f) ? x : NEG_SLOPE * x; }
__device__ __forceinline__ uint_t pack_bf16_rn(float a, float b) {
    __hip_bfloat162 h = __float22bfloat162_rn(make_float2(a, b));  // hw packed cvt
    return *(uint_t*)&h;
}

// ---------------------------------------------------------------------------
// utility
// ---------------------------------------------------------------------------
__global__ void zero_kernel(float* __restrict__ p, size_t n) {
    size_t i = (size_t)blockIdx.x * blockDim.x + threadIdx.x;
    size_t stride = (size_t)gridDim.x * blockDim.x;
    for (; i < n; i += stride) p[i] = 0.0f;
}

// weights only (x is consumed fp32 by the L1 GEMM directly)
#define CN1 (HC_ * INF_)               // Wt1: 512 rows x 1280
#define CN2 (HC_ * HC_)                // Wt2
#define CN3 (HC_ * HC_)                // Wt3 (padded rows)
__global__ void convW_kernel(const float* __restrict__ W1,
                             const float* __restrict__ W2,
                             const float* __restrict__ W3,
                             ushort_t* __restrict__ Wt1,
                             ushort_t* __restrict__ Wt2,
                             ushort_t* __restrict__ Wt3) {
    int i = blockIdx.x * blockDim.x + threadIdx.x;
    if (i < CN1) {
        int n = i / INF_, k = i - n * INF_;
        Wt1[i] = f2bf(W1[(size_t)k * HC_ + n]);
    } else if (i < CN1 + CN2) {
        int j = i - CN1;
        int n = j / HC_, k = j - n * HC_;
        Wt2[j] = f2bf(W2[(size_t)k * HC_ + n]);
    } else if (i < CN1 + CN2 + CN3) {
        int j = i - CN1 - CN2;
        int n = j / HC_, k = j - n * HC_;
        Wt3[j] = (n < OUTF_) ? f2bf(W3[(size_t)k * OUTF_ + n]) : (ushort_t)0;
    }
}

// ---------------------------------------------------------------------------
// CSR build (by destination)
// ---------------------------------------------------------------------------
__global__ void count_kernel(const int* __restrict__ dst, int* __restrict__ counts, int E) {
    int e = blockIdx.x * blockDim.x + threadIdx.x;
    if (e < E) atomicAdd(&counts[dst[e]], 1);
}

__global__ __launch_bounds__(256) void scan1_kernel(const int* __restrict__ counts,
                                                    int* __restrict__ offsets,
                                                    int* __restrict__ bsum, int n) {
    __shared__ int tmp[256];
    int b = blockIdx.x, t = threadIdx.x;
    int i = b * 256 + t;
    int v = (i < n) ? counts[i] : 0;
    tmp[t] = v;
    __syncthreads();
    for (int off = 1; off < 256; off <<= 1) {
        int u = (t >= off) ? tmp[t - off] : 0;
        __syncthreads();
        tmp[t] += u;
        __syncthreads();
    }
    if (i < n) offsets[i] = tmp[t] - v;
    if (t == 255) bsum[b] = tmp[t];
}

__global__ __launch_bounds__(256) void scan3b_kernel(int* __restrict__ offsets,
                                                     int* __restrict__ cursor,
                                                     const int* __restrict__ bsum,
                                                     int nb, int n) {
    __shared__ int base_sh, tot_sh;
    int b = blockIdx.x, t = threadIdx.x;
    if (t == 0) {
        int acc = 0, tot = 0;
        for (int k = 0; k < nb; ++k) { if (k < b) acc += bsum[k]; tot += bsum[k]; }
        base_sh = acc; tot_sh = tot;
    }
    __syncthreads();
    int i = b * 256 + t;
    if (i < n) {
        int v = offsets[i] + base_sh;
        offsets[i] = v;
        cursor[i] = v;
    }
    if (b == nb - 1 && t == 0) offsets[n] = tot_sh;
}

__global__ void scatter_kernel(const int* __restrict__ src, const int* __restrict__ dst,
                               int* __restrict__ cursor, int* __restrict__ esrc, int E) {
    int e = blockIdx.x * blockDim.x + threadIdx.x;
    if (e < E) {
        int p = atomicAdd(&cursor[dst[e]], 1);
        esrc[p] = src[e];
    }
}

// ---------------------------------------------------------------------------
// bf16 MFMA GEMM with fused attention-logit epilogue.
//   OCCUPANCY-FIRST retile: 32x64 tile, BK=64 -> 313x8 = 2500 blocks
//   (~8 resident blocks/CU = near-full 32 waves/CU; evidence R4/R5/R7/R9:
//   GEMM time tracks resident-wave count, nothing else). acc = 8 VGPR/lane.
//   AF32: A fp32 converted during staging with packed hw cvt (RNE).
//   XCD-swizzled 1-D grid keeps A L2-resident per XCD.
// ---------------------------------------------------------------------------
#define LDTK 72

template<bool AF32>
__global__ __launch_bounds__(256) void gemm_fused_kernel(
    const void* __restrict__ Araw,     // [M][K] bf16 or fp32
    const ushort_t* __restrict__ Bt,   // [512][K] bf16 (transposed, padded)
    ushort_t* __restrict__ Cb,         // [M][512] bf16
    const float* __restrict__ avS,     // a_src flat [N]
    const float* __restrict__ avD,     // a_dst flat [N]
    float* __restrict__ s_log,         // [M][H] (pre-zeroed)
    float* __restrict__ d_log,         // [M][H]
    int M, int K, int N, int H, int nMB)
{
    __shared__ __align__(16) ushort_t As[32 * LDTK];
    __shared__ __align__(16) ushort_t Bs[64 * LDTK];

    int id = blockIdx.x;
    int mb = (id >> 6) * 8 + (id & 7);
    int nb = (id >> 3) & 7;
    if (mb >= nMB) return;
    int m0 = mb * 32, n0 = nb * 64;

    int tid  = threadIdx.x;
    int lane = tid & 63;
    int w    = tid >> 6;
    int wm   = (w & 1) * 16;       // wave m-offset (16 rows)
    int wn   = (w >> 1) * 32;      // wave n-offset (32 cols)
    int quad = lane >> 4;
    int c16  = lane & 15;

    f32x4 acc[2];
#pragma unroll
    for (int j = 0; j < 2; ++j)
#pragma unroll
        for (int r = 0; r < 4; ++r) acc[j][r] = 0.0f;

    for (int k0 = 0; k0 < K; k0 += 64) {
        // ---- stage A tile 32x64 ----
        if (AF32) {
            const float* A = (const float*)Araw;
            // 512 float4 chunks -> 2 per thread
#pragma unroll
            for (int t = 0; t < 2; ++t) {
                int ci = t * 256 + tid;
                int row = ci >> 4;            // 16 float4 per row
                int c4 = (ci & 15) * 4;
                int gm = m0 + row;
                if (gm > M - 1) gm = M - 1;
                float4 av = *(const float4*)(A + (size_t)gm * K + k0 + c4);
                *(uint2*)&As[row * LDTK + c4] =
                    make_uint2(pack_bf16_rn(av.x, av.y), pack_bf16_rn(av.z, av.w));
            }
        } else {
            const ushort_t* A = (const ushort_t*)Araw;
            // 256 uint4 chunks -> 1 per thread
            int row = tid >> 3;
            int kc = (tid & 7) * 8;
            int gm = m0 + row;
            if (gm > M - 1) gm = M - 1;
            uint4 av = *(const uint4*)(A + (size_t)gm * K + k0 + kc);
            *(uint4*)&As[row * LDTK + kc] = av;
        }
        // ---- stage B tile 64x64: 512 uint4 chunks -> 2 per thread ----
#pragma unroll
        for (int t = 0; t < 2; ++t) {
            int ci = t * 256 + tid;
            int row = ci >> 3;
            int kc = (ci & 7) * 8;
            uint4 bv = *(const uint4*)(Bt + (size_t)(n0 + row) * K + k0 + kc);
            *(uint4*)&Bs[row * LDTK + kc] = bv;
        }
        __syncthreads();

#pragma unroll
        for (int ks = 0; ks < 2; ++ks) {
            short8x af = *(const short8x*)&As[(wm + c16) * LDTK + ks * 32 + quad * 8];
            short8x bf0 = *(const short8x*)&Bs[(wn +      c16) * LDTK + ks * 32 + quad * 8];
            short8x bf1 = *(const short8x*)&Bs[(wn + 16 + c16) * LDTK + ks * 32 + quad * 8];
            acc[0] = __builtin_amdgcn_mfma_f32_16x16x32_bf16(af, bf0, acc[0], 0, 0, 0);
            acc[1] = __builtin_amdgcn_mfma_f32_16x16x32_bf16(af, bf1, acc[1], 0, 0, 0);
        }
        __syncthreads();
    }

    // ---- epilogue: C store + logit partials ----
    int col0 = n0 + wn + c16;
    int col1 = col0 + 16;
    float as0 = (col0 < N) ? avS[col0] : 0.f;
    float as1 = (col1 < N) ? avS[col1] : 0.f;
    float ad0 = (col0 < N) ? avD[col0] : 0.f;
    float ad1 = (col1 < N) ? avD[col1] : 0.f;

    float sv[4], dv[4];
#pragma unroll
    for (int r = 0; r < 4; ++r) {
        float v0 = acc[0][r];
        float v1 = acc[1][r];
        sv[r] = v0 * as0 + v1 * as1;
        dv[r] = v0 * ad0 + v1 * ad1;
        int row = m0 + wm + quad * 4 + r;
        if (row < M) {
            Cb[(size_t)row * 512 + col0] = f2bf(v0);
            Cb[(size_t)row * 512 + col1] = f2bf(v1);
        }
    }
#pragma unroll
    for (int off = 1; off < 16; off <<= 1) {
#pragma unroll
        for (int i = 0; i < 4; ++i) {
            sv[i] += __shfl_xor(sv[i], off);
            dv[i] += __shfl_xor(dv[i], off);
        }
    }
    if (c16 == 0) {
        int hb = (H == 4) ? (n0 >> 7) : 0;
#pragma unroll
        for (int r = 0; r < 4; ++r) {
            int row = m0 + wm + quad * 4 + r;
            if (row < M) {
                atomicAdd(&s_log[row * H + hb], sv[r]);
                atomicAdd(&d_log[row * H + hb], dv[r]);
            }
        }
    }
}

// ---------------------------------------------------------------------------
// FUSED edge softmax + weighted gather-aggregate (wave-per-node, 8-deep MLP).
// ---------------------------------------------------------------------------
__device__ __forceinline__ void acc8(float* acc, uint4 q, float w) {
    acc[0] += w * bf_lo(q.x); acc[1] += w * bf_hi(q.x);
    acc[2] += w * bf_lo(q.y); acc[3] += w * bf_hi(q.y);
    acc[4] += w * bf_lo(q.z); acc[5] += w * bf_hi(q.z);
    acc[6] += w * bf_lo(q.w); acc[7] += w * bf_hi(q.w);
}

template<int H>
__global__ __launch_bounds__(256) void softagg_kernel(
    const uint4* __restrict__ xpb4,     // [node][64] (512 bf16 / row)
    const float* __restrict__ s,        // [node][H]
    const float* __restrict__ dlog,     // [node][H]
    const int* __restrict__ offsets, const int* __restrict__ esrc,
    float* __restrict__ ew,             // [E][H] scratch
    const float* __restrict__ bias,     // [OUTC]
    float* __restrict__ out,            // [node][ldo]
    int OUTC, int ldo)
{
    int node = blockIdx.x * 4 + (threadIdx.x >> 6);
    if (node >= NNODES) return;
    int lane = threadIdx.x & 63;
    int e0 = offsets[node], e1 = offsets[node + 1];

    // ---- softmax phase ----
    float dh[H], selfe[H], mh[H], zh[H];
#pragma unroll
    for (int h = 0; h < H; ++h) {
        dh[h] = dlog[node * H + h];
        selfe[h] = lrelu(s[node * H + h] + dh[h]);
        mh[h] = selfe[h];
        zh[h] = 0.f;
    }
    for (int j = e0 + lane; j < e1; j += 64) {
        int src = esrc[j];
        if (H == 4) {
            float4 sv = ((const float4*)s)[src];
            mh[0] = fmaxf(mh[0], lrelu(sv.x + dh[0]));
            mh[1] = fmaxf(mh[1], lrelu(sv.y + dh[1]));
            mh[2] = fmaxf(mh[2], lrelu(sv.z + dh[2]));
            mh[3] = fmaxf(mh[3], lrelu(sv.w + dh[3]));
        } else {
#pragma unroll
            for (int h = 0; h < H; ++h)
                mh[h] = fmaxf(mh[h], lrelu(s[src * H + h] + dh[h]));
        }
    }
#pragma unroll
    for (int h = 0; h < H; ++h)
        for (int off = 32; off > 0; off >>= 1)
            mh[h] = fmaxf(mh[h], __shfl_xor(mh[h], off));

    for (int j = e0 + lane; j < e1; j += 64) {
        int src = esrc[j];
        if (H == 4) {
            float4 sv = ((const float4*)s)[src];
            float w0 = __expf(lrelu(sv.x + dh[0]) - mh[0]);
            float w1 = __expf(lrelu(sv.y + dh[1]) - mh[1]);
            float w2 = __expf(lrelu(sv.z + dh[2]) - mh[2]);
            float w3 = __expf(lrelu(sv.w + dh[3]) - mh[3]);
            ((float4*)ew)[j] = make_float4(w0, w1, w2, w3);
            zh[0] += w0; zh[1] += w1; zh[2] += w2; zh[3] += w3;
        } else {
#pragma unroll
            for (int h = 0; h < H; ++h) {
                float w = __expf(lrelu(s[src * H + h] + dh[h]) - mh[h]);
                ew[(size_t)j * H + h] = w;
                zh[h] += w;
            }
        }
    }
#pragma unroll
    for (int h = 0; h < H; ++h)
        for (int off = 32; off > 0; off >>= 1)
            zh[h] += __shfl_xor(zh[h], off);

    float ws_[H], zi_[H];
#pragma unroll
    for (int h = 0; h < H; ++h) {
        ws_[h] = __expf(selfe[h] - mh[h]);
        zi_[h] = 1.0f / (zh[h] + ws_[h]);
    }
    int hg = (H == 4) ? (lane >> 4) : 0;
    float ws, zi;
    if (H == 4) {
        ws = (hg == 0) ? ws_[0] : (hg == 1) ? ws_[1] : (hg == 2) ? ws_[2] : ws_[3];
        zi = (hg == 0) ? zi_[0] : (hg == 1) ? zi_[1] : (hg == 2) ? zi_[2] : zi_[3];
    } else { ws = ws_[0]; zi = zi_[0]; }

    // ---- gather phase (8-deep) ----
    uint4 p = xpb4[(size_t)node * 64 + lane];
    float acc[8];
    acc[0] = ws * bf_lo(p.x); acc[1] = ws * bf_hi(p.x);
    acc[2] = ws * bf_lo(p.y); acc[3] = ws * bf_hi(p.y);
    acc[4] = ws * bf_lo(p.z); acc[5] = ws * bf_hi(p.z);
    acc[6] = ws * bf_lo(p.w); acc[7] = ws * bf_hi(p.w);

    int j = e0;
    for (; j + 7 < e1; j += 8) {
        int ss[8]; float ww[8]; uint4 qq[8];
#pragma unroll
        for (int t = 0; t < 8; ++t) ss[t] = esrc[j + t];
#pragma unroll
        for (int t = 0; t < 8; ++t) ww[t] = ew[(size_t)(j + t) * H + hg];
#pragma unroll
        for (int t = 0; t < 8; ++t) qq[t] = xpb4[(size_t)ss[t] * 64 + lane];
#pragma unroll
        for (int t = 0; t < 8; ++t) acc8(acc, qq[t], ww[t]);
    }
    for (; j + 3 < e1; j += 4) {
        int s0 = esrc[j], s1 = esrc[j + 1], s2 = esrc[j + 2], s3 = esrc[j + 3];
        float w0 = ew[(size_t)j * H + hg];
        float w1 = ew[(size_t)(j + 1) * H + hg];
        float w2 = ew[(size_t)(j + 2) * H + hg];
        float w3 = ew[(size_t)(j + 3) * H + hg];
        uint4 q0 = xpb4[(size_t)s0 * 64 + lane];
        uint4 q1 = xpb4[(size_t)s1 * 64 + lane];
        uint4 q2 = xpb4[(size_t)s2 * 64 + lane];
        uint4 q3 = xpb4[(size_t)s3 * 64 + lane];
        acc8(acc, q0, w0);
        acc8(acc, q1, w1);
        acc8(acc, q2, w2);
        acc8(acc, q3, w3);
    }
    for (; j < e1; ++j) {
        int s0 = esrc[j];
        float w0 = ew[(size_t)j * H + hg];
        uint4 q0 = xpb4[(size_t)s0 * 64 + lane];
        acc8(acc, q0, w0);
    }

    int cbase = lane * 8;
    size_t ob = (size_t)node * ldo + cbase;
    if (cbase + 7 < OUTC) {
        float4 o0 = make_float4(acc[0] * zi + bias[cbase + 0], acc[1] * zi + bias[cbase + 1],
                                acc[2] * zi + bias[cbase + 2], acc[3] * zi + bias[cbase + 3]);
        float4 o1 = make_float4(acc[4] * zi + bias[cbase + 4], acc[5] * zi + bias[cbase + 5],
                                acc[6] * zi + bias[cbase + 6], acc[7] * zi + bias[cbase + 7]);
        *(float4*)(out + ob) = o0;
        *(float4*)(out + ob + 4) = o1;
    } else {
#pragma unroll
        for (int k = 0; k < 8; ++k) {
            int c = cbase + k;
            if (c < OUTC) out[ob + k] = acc[k] * zi + bias[c];
        }
    }
}

// ---------------------------------------------------------------------------
// BatchNorm: stats (64-block partials, folds next-layer logit zeroing) ->
// tiny finalize (scale/shift) -> wide apply+ELU+pack.
// ---------------------------------------------------------------------------
__global__ __launch_bounds__(512) void bn_stats_kernel(const float* __restrict__ h,
                                                       float* __restrict__ psum,
                                                       float* __restrict__ psumsq,
                                                       float* __restrict__ zptr, int zcount) {
    int c = threadIdx.x;  // 512
    int b = blockIdx.x;   // 64
    for (int i = b * 512 + c; i < zcount; i += 64 * 512) zptr[i] = 0.f;
    float sm = 0.f, sq = 0.f;
    for (int r = b; r < NNODES; r += 64) {
        float v = h[(size_t)r * 512 + c];
        sm += v;
        sq += v * v;
    }
    psum[b * 512 + c] = sm;
    psumsq[b * 512 + c] = sq;
}

__global__ __launch_bounds__(512) void bn_finalize_kernel(const float* __restrict__ psum,
                                                          const float* __restrict__ psumsq,
                                                          const float* __restrict__ gamma,
                                                          const float* __restrict__ beta,
                                                          float* __restrict__ scale,
                                                          float* __restrict__ shift) {
    int c = threadIdx.x;
    float sm = 0.f, sq = 0.f;
    for (int b = 0; b < 64; ++b) {
        sm += psum[b * 512 + c];
        sq += psumsq[b * 512 + c];
    }
    const float invN = 1.0f / (float)NNODES;
    float mu = sm * invN;
    float var = sq * invN - mu * mu;
    float sc = gamma[c] * rsqrtf(var + BN_EPS);
    scale[c] = sc;
    shift[c] = beta[c] - mu * sc;
}

__global__ __launch_bounds__(256) void bn_apply_kernel(const float* __restrict__ h,
                                                       const float* __restrict__ scale,
                                                       const float* __restrict__ shift,
                                                       uint_t* __restrict__ hbf) {
    int t = threadIdx.x, b = blockIdx.x;   // grid = 256
    int c0 = t * 2, c1 = c0 + 1;
    float sc0 = scale[c0], sc1 = scale[c1];
    float sh0 = shift[c0], sh1 = shift[c1];
    for (int r = b; r < NNODES; r += 256) {
        float2 hv = ((const float2*)(h + (size_t)r * 512))[t];
        float v0 = hv.x * sc0 + sh0;
        float v1 = hv.y * sc1 + sh1;
        v0 = (v0 > 0.f) ? v0 : (__expf(v0) - 1.0f);
        v1 = (v1 > 0.f) ? v1 : (__expf(v1) - 1.0f);
        hbf[r * 256 + t] = ((uint_t)f2bf(v1) << 16) | (uint_t)f2bf(v0);
    }
}

// ---------------------------------------------------------------------------
// launch — 18 dispatches
// ---------------------------------------------------------------------------
extern "C" void kernel_launch(void* const* d_in, const int* in_sizes, int n_in,
                              void* d_out, int out_size, void* d_ws, size_t ws_size,
                              hipStream_t stream) {
    const float* x      = (const float*)d_in[0];
    const int*   ei     = (const int*)d_in[1];
    const float* W1     = (const float*)d_in[2];
    const float* a_src1 = (const float*)d_in[3];
    const float* a_dst1 = (const float*)d_in[4];
    const float* b1     = (const float*)d_in[5];
    const float* g1     = (const float*)d_in[6];
    const float* be1    = (const float*)d_in[7];
    const float* W2     = (const float*)d_in[8];
    const float* a_src2 = (const float*)d_in[9];
    const float* a_dst2 = (const float*)d_in[10];
    const float* b2     = (const float*)d_in[11];
    const float* g2     = (const float*)d_in[12];
    const float* be2    = (const float*)d_in[13];
    const float* W3     = (const float*)d_in[14];
    const float* a_src3 = (const float*)d_in[15];
    const float* a_dst3 = (const float*)d_in[16];
    const float* b3     = (const float*)d_in[17];
    float* out = (float*)d_out;

    const int* e_src = ei;           // edge_index[0]
    const int* e_dst = ei + NEDGES;  // edge_index[1]

    // ---- workspace layout ----
    char* w = (char*)d_ws;
    float*    hbuf = (float*)w;                               // 20.48 MB
    float*    ew   = (float*)(w + (size_t)NNODES * HC_ * sizeof(float));  // 5.12 MB
    w += (size_t)NNODES * INF_ * sizeof(ushort_t);            // 25.6 MB region
    uint_t* xpb = (uint_t*)w;  w += (size_t)NNODES * HC_ * sizeof(ushort_t);
    uint_t* hbf = (uint_t*)w;  w += (size_t)NNODES * HC_ * sizeof(ushort_t);
    ushort_t* Wt1 = (ushort_t*)w; w += (size_t)HC_ * INF_ * sizeof(ushort_t);
    ushort_t* Wt2 = (ushort_t*)w; w += (size_t)HC_ * HC_ * sizeof(ushort_t);
    ushort_t* Wt3 = (ushort_t*)w; w += (size_t)HC_ * HC_ * sizeof(ushort_t);
    // counts | s_log | d_log contiguous -> single zero pass
    int* counts  = (int*)w;    w += NNODES * sizeof(int);
    float* s_log = (float*)w;  w += NNODES * HEADS_ * sizeof(float);
    float* d_log = (float*)w;  w += NNODES * HEADS_ * sizeof(float);
    float* bnscale = (float*)w; w += HC_ * sizeof(float);
    float* bnshift = (float*)w; w += HC_ * sizeof(float);
    float* psum  = (float*)w;  w += 64 * HC_ * sizeof(float);
    float* psumsq= (float*)w;  w += 64 * HC_ * sizeof(float);
    int* offsets = (int*)w;    w += (NNODES + 1) * sizeof(int);
    int* cursor  = (int*)w;    w += NNODES * sizeof(int);
    int* esrc    = (int*)w;    w += NEDGES * sizeof(int);
    int* bsum    = (int*)w;    w += 64 * sizeof(int);

    const int nMB = (NNODES + 31) / 32;              // 313 row blocks (32 rows)
    const int gemmBlocks = ((nMB + 7) / 8) * 64;     // 2560 (swizzled 1-D grid)
    const int aggGrid = (NNODES + 3) / 4;            // 2500
    const int scanBlocks = (NNODES + 255) / 256;     // 40

    zero_kernel<<<64, 256, 0, stream>>>((float*)counts, NNODES + 2 * NNODES * HEADS_);
    count_kernel<<<(NEDGES + 255) / 256, 256, 0, stream>>>(e_dst, counts, NEDGES);
    scan1_kernel<<<scanBlocks, 256, 0, stream>>>(counts, offsets, bsum, NNODES);
    scan3b_kernel<<<scanBlocks, 256, 0, stream>>>(offsets, cursor, bsum, scanBlocks, NNODES);
    scatter_kernel<<<(NEDGES + 255) / 256, 256, 0, stream>>>(e_src, e_dst, cursor, esrc, NEDGES);
    {
        int TOT = CN1 + CN2 + CN3;
        convW_kernel<<<(TOT + 255) / 256, 256, 0, stream>>>(W1, W2, W3, Wt1, Wt2, Wt3);
    }

    // ---- Layer 1 (GEMM reads x fp32 directly) ----
    gemm_fused_kernel<true><<<gemmBlocks, 256, 0, stream>>>(x, Wt1, (ushort_t*)xpb,
        a_src1, a_dst1, s_log, d_log, NNODES, INF_, HC_, HEADS_, nMB);
    softagg_kernel<HEADS_><<<aggGrid, 256, 0, stream>>>((const uint4*)xpb, s_log, d_log,
        offsets, esrc, ew, b1, hbuf, HC_, HC_);
    bn_stats_kernel<<<64, 512, 0, stream>>>(hbuf, psum, psumsq, s_log, 2 * NNODES * HEADS_);
    bn_finalize_kernel<<<1, 512, 0, stream>>>(psum, psumsq, g1, be1, bnscale, bnshift);
    bn_apply_kernel<<<256, 256, 0, stream>>>(hbuf, bnscale, bnshift, hbf);

    // ---- Layer 2 ----
    gemm_fused_kernel<false><<<gemmBlocks, 256, 0, stream>>>(hbf, Wt2, (ushort_t*)xpb,
        a_src2, a_dst2, s_log, d_log, NNODES, HC_, HC_, HEADS_, nMB);
    softagg_kernel<HEADS_><<<aggGrid, 256, 0, stream>>>((const uint4*)xpb, s_log, d_log,
        offsets, esrc, ew, b2, hbuf, HC_, HC_);
    bn_stats_kernel<<<64, 512, 0, stream>>>(hbuf, psum, psumsq, s_log, 2 * NNODES * HEADS_);
    bn_finalize_kernel<<<1, 512, 0, stream>>>(psum, psumsq, g2, be2, bnscale, bnshift);
    bn_apply_kernel<<<256, 256, 0, stream>>>(hbuf, bnscale, bnshift, hbf);

    // ---- Layer 3 (H=1, N=500) ----
    gemm_fused_kernel<false><<<gemmBlocks, 256, 0, stream>>>(hbf, Wt3, (ushort_t*)xpb,
        a_src3, a_dst3, s_log, d_log, NNODES, HC_, OUTF_, 1, nMB);
    softagg_kernel<1><<<aggGrid, 256, 0, stream>>>((const uint4*)xpb, s_log, d_log,
        offsets, esrc, ew, b3, out, OUTF_, OUTF_);
}